// Round 13
// baseline (381.444 us; speedup 1.0000x reference)
//
#include <hip/hip_runtime.h>

typedef unsigned short u16;
typedef unsigned int u32;
typedef __attribute__((ext_vector_type(4))) float f32x4;
typedef __attribute__((ext_vector_type(8))) short bf16x8;
typedef __attribute__((ext_vector_type(4))) unsigned short u16x4;
typedef __attribute__((ext_vector_type(8))) unsigned short u16x8;

#define NH 16
#define HD 128
#define TT 256
#define CDIM 2048

__device__ __forceinline__ u16 f2bf(float f) {
  u32 u = __float_as_uint(f);
  u = (u + 0x7fffu + ((u >> 16) & 1u)) >> 16;
  return (u16)u;
}
__device__ __forceinline__ float bf2f(u16 h) {
  return __uint_as_float(((u32)h) << 16);
}
__device__ __forceinline__ void gload_lds16(const u16* g, u16* l) {
  __builtin_amdgcn_global_load_lds((__attribute__((address_space(1))) void*)g,
                                   (__attribute__((address_space(3))) void*)l, 16, 0, 0);
}

#define BAR() __builtin_amdgcn_s_barrier()
#define SCB() __builtin_amdgcn_sched_barrier(0)
#define WL0()                                          \
  {                                                    \
    asm volatile("s_waitcnt lgkmcnt(0)" ::: "memory"); \
    SCB();                                             \
  }
#define WV8()                                         \
  {                                                   \
    asm volatile("s_waitcnt vmcnt(8)" ::: "memory");  \
    SCB();                                            \
  }
#define WVL0()                                                   \
  {                                                              \
    asm volatile("s_waitcnt vmcnt(0) lgkmcnt(0)" ::: "memory");  \
    SCB();                                                       \
  }
#define P1() __builtin_amdgcn_s_setprio(1)
#define P0() __builtin_amdgcn_s_setprio(0)

// ---------------- convert f32 -> bf16, 8 elems/thread ----------------
__global__ __launch_bounds__(256) void cvt_bf16_kernel(const float* __restrict__ src,
                                                       u16* __restrict__ dst, int n8) {
  int i = blockIdx.x * 256 + threadIdx.x;
  if (i >= n8) return;
  const float4* s4 = (const float4*)src;
  float4 a = s4[i * 2];
  float4 b = s4[i * 2 + 1];
  u16x8 r;
  r[0] = f2bf(a.x); r[1] = f2bf(a.y); r[2] = f2bf(a.z); r[3] = f2bf(a.w);
  r[4] = f2bf(b.x); r[5] = f2bf(b.y); r[6] = f2bf(b.z); r[7] = f2bf(b.w);
  *(u16x8*)(dst + (long)i * 8) = r;
}

// all four weight matrices in one launch
__global__ __launch_bounds__(256) void cvt_w_kernel(const float* __restrict__ wq,
                                                    const float* __restrict__ wk,
                                                    const float* __restrict__ wv,
                                                    const float* __restrict__ wo,
                                                    u16* __restrict__ wqkv,
                                                    u16* __restrict__ wobf) {
  int i = blockIdx.x * 256 + threadIdx.x;
  int seg = i >> 19;
  int r8 = i & 524287;
  const float* s = (seg == 0) ? wq : (seg == 1) ? wk : (seg == 2) ? wv : wo;
  u16* d = (seg == 3) ? wobf : (wqkv + (long)seg * 4194304);
  const float4* s4 = (const float4*)s;
  float4 a = s4[r8 * 2];
  float4 b = s4[r8 * 2 + 1];
  u16x8 r;
  r[0] = f2bf(a.x); r[1] = f2bf(a.y); r[2] = f2bf(a.z); r[3] = f2bf(a.w);
  r[4] = f2bf(b.x); r[5] = f2bf(b.y); r[6] = f2bf(b.z); r[7] = f2bf(b.w);
  *(u16x8*)(d + (long)r8 * 8) = r;
}

// ---------------- rope tables: [256][64] cos,sin ----------------
__global__ void rope_tables_kernel(float* __restrict__ cosT, float* __restrict__ sinT) {
  int i = blockIdx.x * 256 + threadIdx.x;  // 16384
  int t = i >> 6, d = i & 63;
  float inv = __expf(-(float)d * (9.210340371976184f / 64.0f));
  float a = (float)t * inv;
  cosT[i] = cosf(a);
  sinT[i] = sinf(a);
}

// ---------------- 256x256 GEMM  C = A * B^T (R12/R7 structure, frozen) ----------------
#define LDA_(CB)                                                     \
  _Pragma("unroll") for (int f = 0; f < 4; ++f)                      \
  _Pragma("unroll") for (int ks = 0; ks < 2; ++ks)                   \
      fa[f][ks] = *(const bf16x8*)&lds[(CB) + wr64 + f * 1024 + lb[ks]];

#define LDB_(CB, Q)                                                  \
  _Pragma("unroll") for (int fn = 0; fn < 2; ++fn)                   \
  _Pragma("unroll") for (int ks = 0; ks < 2; ++ks)                   \
      fb[fn][ks] = *(const bf16x8*)&lds[(CB) + wbB + (Q)*2048 + fn * 1024 + lb[ks]];

#define MMQ(Q)                                                       \
  _Pragma("unroll") for (int ks = 0; ks < 2; ++ks)                   \
  _Pragma("unroll") for (int f = 0; f < 4; ++f)                      \
  _Pragma("unroll") for (int fn = 0; fn < 2; ++fn)                   \
      acc[f][(Q)*2 + fn] = __builtin_amdgcn_mfma_f32_16x16x32_bf16(  \
          fa[f][ks], fb[fn][ks], acc[f][(Q)*2 + fn], 0, 0, 0);

template <int MODE>
__global__ __launch_bounds__(512, 2) void gemm256(const u16* __restrict__ A,
                                                  const u16* __restrict__ Bt,
                                                  float* __restrict__ Cf, u16* __restrict__ Qo,
                                                  u16* __restrict__ Ko, u16* __restrict__ Vo,
                                                  const float* __restrict__ cosT,
                                                  const float* __restrict__ sinT,
                                                  int M, int N, int K, int GX) {
  __shared__ u16 lds[65536];  // buf c at c*32768: [A 4x4096][B 4x4096] u16
  const int wg = blockIdx.x;
  const int bn = wg % GX, bm = wg / GX;
  const int tid = threadIdx.x, wid = tid >> 6, lane = tid & 63;
  const int lr = lane & 15, lg = lane >> 4;
  const int wr = (wid >> 1) * 64;      // wave A-row base in [0,256)
  const int wch = wid & 1;             // wave B-half (C cols wch*128 .. +127)
  const int wr64 = (wid >> 1) * 4096;  // hoisted A base
  const int wbB = 16384 + wch * 8192;  // hoisted B base
  const int NT = K >> 6;
  const long KU = (long)64 * K;
  const u16* Ag = A + (long)(bm * 256) * K;
  const u16* Bg = Bt + (long)(bn * 256) * K;

  int lb[2];
#pragma unroll
  for (int ks = 0; ks < 2; ++ks) lb[ks] = lr * 64 + (((ks * 4 + lg) ^ (lr & 7))) * 8;

  const int csg = ((tid & 7) ^ ((tid >> 3) & 7)) * 8;
  const u16* aBase = Ag + (long)(tid >> 3) * K + csg;
  const u16* bBase = Bg + (long)(tid >> 3) * K + csg;
  auto STGA = [&](int ldso, int u, int kt) {
    if (kt > NT - 1) kt = NT - 1;
    gload_lds16(aBase + (long)u * KU + kt * 64, &lds[ldso + tid * 8]);
  };
  auto STGB = [&](int ldso, int u, int kt) {
    if (kt > NT - 1) kt = NT - 1;
    gload_lds16(bBase + (long)u * KU + kt * 64, &lds[ldso + tid * 8]);
  };

  bf16x8 fa[4][2], fb[2][2];
  const f32x4 zero = {0.f, 0.f, 0.f, 0.f};
  f32x4 acc[4][8];
#pragma unroll
  for (int a = 0; a < 4; ++a)
#pragma unroll
    for (int b = 0; b < 8; ++b) acc[a][b] = zero;

  STGA(0, 0, 0);
  STGA(4096, 1, 0);
  STGA(8192, 2, 0);
  STGA(12288, 3, 0);
  STGB(16384, 0, 0);
  STGB(24576, 2, 0);
  STGB(20480, 1, 0);
  STGB(28672, 3, 0);
  STGA(32768, 0, 1);
  STGA(36864, 1, 1);
  STGA(40960, 2, 1);
  STGA(45056, 3, 1);
  STGB(49152, 0, 1);
  STGB(57344, 2, 1);
  WV8();
  BAR();

#define TILE(CB, OB, T1, T2)       \
  LDA_(CB)                         \
  LDB_(CB, 0)                      \
  STGB((OB) + 20480, 1, T1);       \
  STGB((OB) + 28672, 3, T1);       \
  BAR(); WL0();                    \
  P1(); MMQ(0) P0();               \
  BAR();                           \
  LDB_(CB, 1)                      \
  STGA((CB) + 0, 0, T2);           \
  STGA((CB) + 4096, 1, T2);        \
  BAR(); WL0();                    \
  P1(); MMQ(1) P0();               \
  WV8();                           \
  BAR();                           \
  LDB_(CB, 2)                      \
  STGA((CB) + 8192, 2, T2);        \
  STGA((CB) + 12288, 3, T2);       \
  BAR(); WL0();                    \
  P1(); MMQ(2) P0();               \
  BAR();                           \
  LDB_(CB, 3)                      \
  STGB((CB) + 16384, 0, T2);       \
  STGB((CB) + 24576, 2, T2);       \
  BAR(); WL0();                    \
  P1(); MMQ(3) P0();               \
  WV8();                           \
  BAR();

  const int J = NT >> 1;
  for (int j = 0; j < J; ++j) {
    const int t1 = 2 * j + 1, t2 = 2 * j + 2, t3 = 2 * j + 3;
    TILE(0, 32768, t1, t2)
    TILE(32768, 0, t2, t3)
  }
  WVL0();
  BAR();

  if (MODE == 0) {
#pragma unroll
    for (int f = 0; f < 4; ++f)
#pragma unroll
      for (int j8 = 0; j8 < 8; ++j8)
#pragma unroll
        for (int r = 0; r < 4; ++r) {
          int m = bm * 256 + wr + f * 16 + lg * 4 + r;
          int n = bn * 256 + wch * 128 + (j8 >> 1) * 32 + (j8 & 1) * 16 + lr;
          Cf[(long)m * N + n] = acc[f][j8][r];
        }
  } else {
    const int mat = bn >> 3;
    u16* dst = (mat == 0) ? Qo : ((mat == 1) ? Ko : Vo);
    const float qsc = (mat == 0) ? 0.08838834764831845f : 1.0f;
#pragma unroll
    for (int mh = 0; mh < 2; ++mh) {
      if (mh) BAR();
      if ((wid >> 2) == mh) {
#pragma unroll
        for (int f = 0; f < 4; ++f)
#pragma unroll
          for (int j8 = 0; j8 < 8; ++j8)
#pragma unroll
            for (int r = 0; r < 4; ++r) {
              int rowl = ((wid >> 1) & 1) * 64 + f * 16 + lg * 4 + r;
              int col = wch * 128 + (j8 >> 1) * 32 + (j8 & 1) * 16 + lr;
              lds[rowl * 272 + col] = f2bf(acc[f][j8][r]);
            }
      }
      BAR();
#pragma unroll
      for (int it = 0; it < 8; ++it) {
        int task = it * 512 + tid;
        int tl = task >> 5, c8 = task & 31;
        int hp = c8 >> 4, d0 = (c8 & 15) * 8;
        int t = mh * 128 + tl;
        int head = (bn * 2 + hp) & 15;
        u16x8 v1 = *(const u16x8*)&lds[tl * 272 + hp * 128 + d0];
        u16x8 o;
        if (mat < 2) {
          int dpart = (d0 < 64) ? (d0 + 64) : (d0 - 64);
          u16x8 v2 = *(const u16x8*)&lds[tl * 272 + hp * 128 + dpart];
          int dm = d0 & 63;
          float4 c0 = *(const float4*)(cosT + t * 64 + dm);
          float4 c1 = *(const float4*)(cosT + t * 64 + dm + 4);
          float4 s0 = *(const float4*)(sinT + t * 64 + dm);
          float4 s1 = *(const float4*)(sinT + t * 64 + dm + 4);
          float cc[8] = {c0.x, c0.y, c0.z, c0.w, c1.x, c1.y, c1.z, c1.w};
          float ss[8] = {s0.x, s0.y, s0.z, s0.w, s1.x, s1.y, s1.z, s1.w};
          float sgn = (d0 < 64) ? -1.f : 1.f;
#pragma unroll
          for (int jj = 0; jj < 8; ++jj)
            o[jj] = f2bf((bf2f(v1[jj]) * cc[jj] + sgn * bf2f(v2[jj]) * ss[jj]) * qsc);
        } else {
          o = v1;
        }
        *(u16x8*)(dst + (((long)(bm * NH + head)) * TT + t) * HD + d0) = o;
      }
    }
  }
}

// ---------------- fused causal attention ----------------
// R13: (1) Vt double-XOR swizzle, stride 64 -- element (d,k) at
// d*64 + ((k>>3) ^ (d&7) ^ ((d>>3)&7))*8 + (k&7). Writes (lanes vary d by 8)
// spread via (d>>3)&7 -> 2-way; reads (lanes vary d by 1) spread via d&7 ->
// 2-way. Replaces the 16-way write conflict of the padded-transpose layout.
// (2) LDS 51.8KB + launch_bounds(256,3) -> 3 blocks/CU. (3) heavy-first bids.
__global__ __launch_bounds__(256, 3) void attn_kernel(const u16* __restrict__ Qb,
                                                      const u16* __restrict__ Kb,
                                                      const u16* __restrict__ Vb,
                                                      u16* __restrict__ Ob) {
  __shared__ u16 Ks[64][136];
  __shared__ u16 VtL[128 * 64];
  __shared__ u16 Ps[4][32][72];
  const int bid = blockIdx.x;
  // heavy-first: bids 0..511 are qb=1 (4 chunks), 512..1023 are qb=0 (2 chunks)
  const int qb = (bid < 512) ? 1 : 0;
  const int hb = (bid < 512) ? bid : (bid - 512);
  const int h = hb & 15, b = hb >> 4;
  const int tid = threadIdx.x, wid = tid >> 6, lane = tid & 63;
  const int lr = lane & 15, lg = lane >> 4;
  const u16* qh = Qb + ((long)(b * NH + h)) * TT * HD;
  const u16* kh = Kb + ((long)(b * NH + h)) * TT * HD;
  const u16* vh = Vb + ((long)(b * NH + h)) * TT * HD;
  const int q0 = qb * 128 + wid * 32;

  bf16x8 qf[2][4];
#pragma unroll
  for (int fq = 0; fq < 2; ++fq)
#pragma unroll
    for (int ds = 0; ds < 4; ++ds)
      qf[fq][ds] = *(const bf16x8*)(qh + (long)(q0 + fq * 16 + lr) * HD + ds * 32 + lg * 8);

  const f32x4 zero = {0.f, 0.f, 0.f, 0.f};
  f32x4 oacc[2][8];
#pragma unroll
  for (int fq = 0; fq < 2; ++fq)
#pragma unroll
    for (int fd = 0; fd < 8; ++fd) oacc[fq][fd] = zero;
  float mrow[2][4], lrow[2][4];
#pragma unroll
  for (int fq = 0; fq < 2; ++fq)
#pragma unroll
    for (int r = 0; r < 4; ++r) { mrow[fq][r] = -1e30f; lrow[fq][r] = 0.f; }

  const int nch = (qb == 0) ? 2 : 4;
  for (int kc = 0; kc < nch; ++kc) {
    __syncthreads();
#pragma unroll
    for (int it = 0; it < 4; ++it) {
      int task = it * 256 + tid;
      int r = task >> 4, sg = task & 15;
      u16x8 v = *(const u16x8*)(kh + (long)(kc * 64 + r) * HD + sg * 8);
      *(u16x8*)(&Ks[r][sg * 8]) = v;
    }
    // V transposed into swizzled VtL
#pragma unroll
    for (int it = 0; it < 4; ++it) {
      int task = it * 256 + tid;
      int r = task >> 4, d0 = (task & 15) * 8, hx = task & 7;
      u16x8 v = *(const u16x8*)(vh + (long)(kc * 64 + r) * HD + d0);
      int gbase = (r >> 3), roff = r & 7;
#pragma unroll
      for (int j = 0; j < 8; ++j)
        VtL[(d0 + j) * 64 + ((gbase ^ j ^ hx) << 3) + roff] = v[j];
    }
    __syncthreads();

    f32x4 sacc[2][4];
#pragma unroll
    for (int fq = 0; fq < 2; ++fq)
#pragma unroll
      for (int fk = 0; fk < 4; ++fk) sacc[fq][fk] = zero;
#pragma unroll
    for (int ds = 0; ds < 4; ++ds) {
      bf16x8 kf[4];
#pragma unroll
      for (int fk = 0; fk < 4; ++fk)
        kf[fk] = *(const bf16x8*)(&Ks[fk * 16 + lr][ds * 32 + lg * 8]);
#pragma unroll
      for (int fq = 0; fq < 2; ++fq)
#pragma unroll
        for (int fk = 0; fk < 4; ++fk)
          sacc[fq][fk] =
              __builtin_amdgcn_mfma_f32_16x16x32_bf16(qf[fq][ds], kf[fk], sacc[fq][fk], 0, 0, 0);
    }

#pragma unroll
    for (int fq = 0; fq < 2; ++fq) {
      float mnew[4], alpha[4], psum[4];
#pragma unroll
      for (int r = 0; r < 4; ++r) {
        int qrow = q0 + fq * 16 + lg * 4 + r;
        float cmax = -1e30f;
#pragma unroll
        for (int fk = 0; fk < 4; ++fk) {
          int kcol = kc * 64 + fk * 16 + lr;
          float s = sacc[fq][fk][r];
          if (kcol > qrow) s = -1e30f;
          sacc[fq][fk][r] = s;
          cmax = fmaxf(cmax, s);
        }
#pragma unroll
        for (int off = 1; off < 16; off <<= 1) cmax = fmaxf(cmax, __shfl_xor(cmax, off));
        mnew[r] = fmaxf(mrow[fq][r], cmax);
        alpha[r] = __expf(mrow[fq][r] - mnew[r]);
        mrow[fq][r] = mnew[r];
        psum[r] = 0.f;
      }
#pragma unroll
      for (int fk = 0; fk < 4; ++fk)
#pragma unroll
        for (int r = 0; r < 4; ++r) {
          float p = __expf(sacc[fq][fk][r] - mnew[r]);
          psum[r] += p;
          Ps[wid][fq * 16 + lg * 4 + r][fk * 16 + lr] = f2bf(p);
        }
#pragma unroll
      for (int r = 0; r < 4; ++r) {
        float ps = psum[r];
#pragma unroll
        for (int off = 1; off < 16; off <<= 1) ps += __shfl_xor(ps, off);
        lrow[fq][r] = lrow[fq][r] * alpha[r] + ps;
#pragma unroll
        for (int fd = 0; fd < 8; ++fd) oacc[fq][fd][r] *= alpha[r];
      }
    }

    // O += P @ V  (V^T fragments from swizzled VtL)
#pragma unroll
    for (int ks = 0; ks < 2; ++ks) {
      bf16x8 pf0 = *(const bf16x8*)(&Ps[wid][lr][ks * 32 + lg * 8]);
      bf16x8 pf1 = *(const bf16x8*)(&Ps[wid][16 + lr][ks * 32 + lg * 8]);
#pragma unroll
      for (int fd = 0; fd < 8; ++fd) {
        int drow = fd * 16 + lr;
        int vg = (ks * 4 + lg) ^ (lr & 7) ^ ((2 * fd + (lr >> 3)) & 7);
        bf16x8 vf = *(const bf16x8*)(&VtL[drow * 64 + vg * 8]);
        oacc[0][fd] = __builtin_amdgcn_mfma_f32_16x16x32_bf16(pf0, vf, oacc[0][fd], 0, 0, 0);
        oacc[1][fd] = __builtin_amdgcn_mfma_f32_16x16x32_bf16(pf1, vf, oacc[1][fd], 0, 0, 0);
      }
    }
  }

#pragma unroll
  for (int fq = 0; fq < 2; ++fq)
#pragma unroll
    for (int r = 0; r < 4; ++r) {
      float inv = 1.0f / lrow[fq][r];
      int t = q0 + fq * 16 + lg * 4 + r;
      u16* od = Ob + ((long)(b * TT + t)) * CDIM + h * HD;
#pragma unroll
      for (int fd = 0; fd < 8; ++fd) od[fd * 16 + lr] = f2bf(oacc[fq][fd][r] * inv);
    }
}

extern "C" void kernel_launch(void* const* d_in, const int* in_sizes, int n_in, void* d_out,
                              int out_size, void* d_ws, size_t ws_size, hipStream_t stream) {
  const float* x = (const float*)d_in[0];
  const float* wq = (const float*)d_in[2];
  const float* wk = (const float*)d_in[3];
  const float* wv = (const float*)d_in[4];
  const float* wo = (const float*)d_in[5];

  char* ws = (char*)d_ws;
  u16* xbf = (u16*)(ws);                   // 32 MB; later reused as attn-out [b][t][c]
  u16* wqkv = (u16*)(ws + 33554432);       // 24 MB  [6144][2048]
  u16* wobf = (u16*)(ws + 58720256);       // 8 MB
  u16* qbf = (u16*)(ws + 67108864);        // 32 MB  [b][h][t][d]
  u16* kbf = (u16*)(ws + 100663296);       // 32 MB
  u16* vbf = (u16*)(ws + 134217728);       // 32 MB
  float* cosT = (float*)(ws + 167772160);  // 64 KB
  float* sinT = (float*)(ws + 167837696);  // 64 KB

  cvt_bf16_kernel<<<8192, 256, 0, stream>>>(x, xbf, 2097152);
  cvt_w_kernel<<<8192, 256, 0, stream>>>(wq, wk, wv, wo, wqkv, wobf);
  rope_tables_kernel<<<64, 256, 0, stream>>>(cosT, sinT);

  gemm256<1><<<768, 512, 0, stream>>>(xbf, wqkv, nullptr, qbf, kbf, vbf, cosT, sinT, 8192, 6144,
                                      2048, 24);
  attn_kernel<<<1024, 256, 0, stream>>>(qbf, kbf, vbf, xbf);
  gemm256<0><<<256, 512, 0, stream>>>(xbf, wobf, (float*)d_out, nullptr, nullptr, nullptr, nullptr,
                                      nullptr, 8192, 2048, 2048, 8);
}

// Round 14
// 354.857 us; speedup vs baseline: 1.0749x; 1.0749x over previous
//
#include <hip/hip_runtime.h>

typedef unsigned short u16;
typedef unsigned int u32;
typedef __attribute__((ext_vector_type(4))) float f32x4;
typedef __attribute__((ext_vector_type(8))) short bf16x8;
typedef __attribute__((ext_vector_type(4))) unsigned short u16x4;
typedef __attribute__((ext_vector_type(8))) unsigned short u16x8;

#define NH 16
#define HD 128
#define TT 256
#define CDIM 2048

__device__ __forceinline__ u16 f2bf(float f) {
  u32 u = __float_as_uint(f);
  u = (u + 0x7fffu + ((u >> 16) & 1u)) >> 16;
  return (u16)u;
}
__device__ __forceinline__ float bf2f(u16 h) {
  return __uint_as_float(((u32)h) << 16);
}
__device__ __forceinline__ void gload_lds16(const u16* g, u16* l) {
  __builtin_amdgcn_global_load_lds((__attribute__((address_space(1))) void*)g,
                                   (__attribute__((address_space(3))) void*)l, 16, 0, 0);
}

#define BAR() __builtin_amdgcn_s_barrier()
#define SCB() __builtin_amdgcn_sched_barrier(0)
#define WL0()                                          \
  {                                                    \
    asm volatile("s_waitcnt lgkmcnt(0)" ::: "memory"); \
    SCB();                                             \
  }
#define WV8()                                         \
  {                                                   \
    asm volatile("s_waitcnt vmcnt(8)" ::: "memory");  \
    SCB();                                            \
  }
#define WVL0()                                                   \
  {                                                              \
    asm volatile("s_waitcnt vmcnt(0) lgkmcnt(0)" ::: "memory");  \
    SCB();                                                       \
  }
#define P1() __builtin_amdgcn_s_setprio(1)
#define P0() __builtin_amdgcn_s_setprio(0)

// ---------------- convert f32 -> bf16, 8 elems/thread ----------------
__global__ __launch_bounds__(256) void cvt_bf16_kernel(const float* __restrict__ src,
                                                       u16* __restrict__ dst, int n8) {
  int i = blockIdx.x * 256 + threadIdx.x;
  if (i >= n8) return;
  const float4* s4 = (const float4*)src;
  float4 a = s4[i * 2];
  float4 b = s4[i * 2 + 1];
  u16x8 r;
  r[0] = f2bf(a.x); r[1] = f2bf(a.y); r[2] = f2bf(a.z); r[3] = f2bf(a.w);
  r[4] = f2bf(b.x); r[5] = f2bf(b.y); r[6] = f2bf(b.z); r[7] = f2bf(b.w);
  *(u16x8*)(dst + (long)i * 8) = r;
}

// all four weight matrices in one launch
__global__ __launch_bounds__(256) void cvt_w_kernel(const float* __restrict__ wq,
                                                    const float* __restrict__ wk,
                                                    const float* __restrict__ wv,
                                                    const float* __restrict__ wo,
                                                    u16* __restrict__ wqkv,
                                                    u16* __restrict__ wobf) {
  int i = blockIdx.x * 256 + threadIdx.x;
  int seg = i >> 19;
  int r8 = i & 524287;
  const float* s = (seg == 0) ? wq : (seg == 1) ? wk : (seg == 2) ? wv : wo;
  u16* d = (seg == 3) ? wobf : (wqkv + (long)seg * 4194304);
  const float4* s4 = (const float4*)s;
  float4 a = s4[r8 * 2];
  float4 b = s4[r8 * 2 + 1];
  u16x8 r;
  r[0] = f2bf(a.x); r[1] = f2bf(a.y); r[2] = f2bf(a.z); r[3] = f2bf(a.w);
  r[4] = f2bf(b.x); r[5] = f2bf(b.y); r[6] = f2bf(b.z); r[7] = f2bf(b.w);
  *(u16x8*)(d + (long)r8 * 8) = r;
}

// ---------------- rope tables: [256][64] cos,sin ----------------
__global__ void rope_tables_kernel(float* __restrict__ cosT, float* __restrict__ sinT) {
  int i = blockIdx.x * 256 + threadIdx.x;  // 16384
  int t = i >> 6, d = i & 63;
  float inv = __expf(-(float)d * (9.210340371976184f / 64.0f));
  float a = (float)t * inv;
  cosT[i] = cosf(a);
  sinT[i] = sinf(a);
}

// ---------------- 256x256 GEMM  C = A * B^T (R12/R7 structure, frozen) ----------------
#define LDA_(CB)                                                     \
  _Pragma("unroll") for (int f = 0; f < 4; ++f)                      \
  _Pragma("unroll") for (int ks = 0; ks < 2; ++ks)                   \
      fa[f][ks] = *(const bf16x8*)&lds[(CB) + wr64 + f * 1024 + lb[ks]];

#define LDB_(CB, Q)                                                  \
  _Pragma("unroll") for (int fn = 0; fn < 2; ++fn)                   \
  _Pragma("unroll") for (int ks = 0; ks < 2; ++ks)                   \
      fb[fn][ks] = *(const bf16x8*)&lds[(CB) + wbB + (Q)*2048 + fn * 1024 + lb[ks]];

#define MMQ(Q)                                                       \
  _Pragma("unroll") for (int ks = 0; ks < 2; ++ks)                   \
  _Pragma("unroll") for (int f = 0; f < 4; ++f)                      \
  _Pragma("unroll") for (int fn = 0; fn < 2; ++fn)                   \
      acc[f][(Q)*2 + fn] = __builtin_amdgcn_mfma_f32_16x16x32_bf16(  \
          fa[f][ks], fb[fn][ks], acc[f][(Q)*2 + fn], 0, 0, 0);

template <int MODE>
__global__ __launch_bounds__(512, 2) void gemm256(const u16* __restrict__ A,
                                                  const u16* __restrict__ Bt,
                                                  float* __restrict__ Cf, u16* __restrict__ Qo,
                                                  u16* __restrict__ Ko, u16* __restrict__ Vo,
                                                  const float* __restrict__ cosT,
                                                  const float* __restrict__ sinT,
                                                  int M, int N, int K, int GX) {
  __shared__ u16 lds[65536];  // buf c at c*32768: [A 4x4096][B 4x4096] u16
  const int wg = blockIdx.x;
  const int bn = wg % GX, bm = wg / GX;
  const int tid = threadIdx.x, wid = tid >> 6, lane = tid & 63;
  const int lr = lane & 15, lg = lane >> 4;
  const int wr = (wid >> 1) * 64;      // wave A-row base in [0,256)
  const int wch = wid & 1;             // wave B-half (C cols wch*128 .. +127)
  const int wr64 = (wid >> 1) * 4096;  // hoisted A base
  const int wbB = 16384 + wch * 8192;  // hoisted B base
  const int NT = K >> 6;
  const long KU = (long)64 * K;
  const u16* Ag = A + (long)(bm * 256) * K;
  const u16* Bg = Bt + (long)(bn * 256) * K;

  int lb[2];
#pragma unroll
  for (int ks = 0; ks < 2; ++ks) lb[ks] = lr * 64 + (((ks * 4 + lg) ^ (lr & 7))) * 8;

  const int csg = ((tid & 7) ^ ((tid >> 3) & 7)) * 8;
  const u16* aBase = Ag + (long)(tid >> 3) * K + csg;
  const u16* bBase = Bg + (long)(tid >> 3) * K + csg;
  auto STGA = [&](int ldso, int u, int kt) {
    if (kt > NT - 1) kt = NT - 1;
    gload_lds16(aBase + (long)u * KU + kt * 64, &lds[ldso + tid * 8]);
  };
  auto STGB = [&](int ldso, int u, int kt) {
    if (kt > NT - 1) kt = NT - 1;
    gload_lds16(bBase + (long)u * KU + kt * 64, &lds[ldso + tid * 8]);
  };

  bf16x8 fa[4][2], fb[2][2];
  const f32x4 zero = {0.f, 0.f, 0.f, 0.f};
  f32x4 acc[4][8];
#pragma unroll
  for (int a = 0; a < 4; ++a)
#pragma unroll
    for (int b = 0; b < 8; ++b) acc[a][b] = zero;

  STGA(0, 0, 0);
  STGA(4096, 1, 0);
  STGA(8192, 2, 0);
  STGA(12288, 3, 0);
  STGB(16384, 0, 0);
  STGB(24576, 2, 0);
  STGB(20480, 1, 0);
  STGB(28672, 3, 0);
  STGA(32768, 0, 1);
  STGA(36864, 1, 1);
  STGA(40960, 2, 1);
  STGA(45056, 3, 1);
  STGB(49152, 0, 1);
  STGB(57344, 2, 1);
  WV8();
  BAR();

#define TILE(CB, OB, T1, T2)       \
  LDA_(CB)                         \
  LDB_(CB, 0)                      \
  STGB((OB) + 20480, 1, T1);       \
  STGB((OB) + 28672, 3, T1);       \
  BAR(); WL0();                    \
  P1(); MMQ(0) P0();               \
  BAR();                           \
  LDB_(CB, 1)                      \
  STGA((CB) + 0, 0, T2);           \
  STGA((CB) + 4096, 1, T2);        \
  BAR(); WL0();                    \
  P1(); MMQ(1) P0();               \
  WV8();                           \
  BAR();                           \
  LDB_(CB, 2)                      \
  STGA((CB) + 8192, 2, T2);        \
  STGA((CB) + 12288, 3, T2);       \
  BAR(); WL0();                    \
  P1(); MMQ(2) P0();               \
  BAR();                           \
  LDB_(CB, 3)                      \
  STGB((CB) + 16384, 0, T2);       \
  STGB((CB) + 24576, 2, T2);       \
  BAR(); WL0();                    \
  P1(); MMQ(3) P0();               \
  WV8();                           \
  BAR();

  const int J = NT >> 1;
  for (int j = 0; j < J; ++j) {
    const int t1 = 2 * j + 1, t2 = 2 * j + 2, t3 = 2 * j + 3;
    TILE(0, 32768, t1, t2)
    TILE(32768, 0, t2, t3)
  }
  WVL0();
  BAR();

  if (MODE == 0) {
#pragma unroll
    for (int f = 0; f < 4; ++f)
#pragma unroll
      for (int j8 = 0; j8 < 8; ++j8)
#pragma unroll
        for (int r = 0; r < 4; ++r) {
          int m = bm * 256 + wr + f * 16 + lg * 4 + r;
          int n = bn * 256 + wch * 128 + (j8 >> 1) * 32 + (j8 & 1) * 16 + lr;
          Cf[(long)m * N + n] = acc[f][j8][r];
        }
  } else {
    const int mat = bn >> 3;
    u16* dst = (mat == 0) ? Qo : ((mat == 1) ? Ko : Vo);
    const float qsc = (mat == 0) ? 0.08838834764831845f : 1.0f;
#pragma unroll
    for (int mh = 0; mh < 2; ++mh) {
      if (mh) BAR();
      if ((wid >> 2) == mh) {
#pragma unroll
        for (int f = 0; f < 4; ++f)
#pragma unroll
          for (int j8 = 0; j8 < 8; ++j8)
#pragma unroll
            for (int r = 0; r < 4; ++r) {
              int rowl = ((wid >> 1) & 1) * 64 + f * 16 + lg * 4 + r;
              int col = wch * 128 + (j8 >> 1) * 32 + (j8 & 1) * 16 + lr;
              lds[rowl * 272 + col] = f2bf(acc[f][j8][r]);
            }
      }
      BAR();
#pragma unroll
      for (int it = 0; it < 8; ++it) {
        int task = it * 512 + tid;
        int tl = task >> 5, c8 = task & 31;
        int hp = c8 >> 4, d0 = (c8 & 15) * 8;
        int t = mh * 128 + tl;
        int head = (bn * 2 + hp) & 15;
        u16x8 v1 = *(const u16x8*)&lds[tl * 272 + hp * 128 + d0];
        u16x8 o;
        if (mat < 2) {
          int dpart = (d0 < 64) ? (d0 + 64) : (d0 - 64);
          u16x8 v2 = *(const u16x8*)&lds[tl * 272 + hp * 128 + dpart];
          int dm = d0 & 63;
          float4 c0 = *(const float4*)(cosT + t * 64 + dm);
          float4 c1 = *(const float4*)(cosT + t * 64 + dm + 4);
          float4 s0 = *(const float4*)(sinT + t * 64 + dm);
          float4 s1 = *(const float4*)(sinT + t * 64 + dm + 4);
          float cc[8] = {c0.x, c0.y, c0.z, c0.w, c1.x, c1.y, c1.z, c1.w};
          float ss[8] = {s0.x, s0.y, s0.z, s0.w, s1.x, s1.y, s1.z, s1.w};
          float sgn = (d0 < 64) ? -1.f : 1.f;
#pragma unroll
          for (int jj = 0; jj < 8; ++jj)
            o[jj] = f2bf((bf2f(v1[jj]) * cc[jj] + sgn * bf2f(v2[jj]) * ss[jj]) * qsc);
        } else {
          o = v1;
        }
        *(u16x8*)(dst + (((long)(bm * NH + head)) * TT + t) * HD + d0) = o;
      }
    }
  }
}

// ---------------- fused causal attention ----------------
// R14: R12 structure restored (R13's swizzle regressed -33us). One change per
// guide lesson #7 (m169): K per head = 64KB is L1/L2-resident and all 4 waves
// read IDENTICAL K-fragment addresses -> drop K LDS staging, read K fragments
// directly from global (per-lane contiguous 16B dwordx4; 16x64B segments/wave).
// Deletes Ks (17.4KB): LDS 54.2 -> 36.9KB -> 4 blocks/CU (was 2) for this
// latency-bound kernel. V transpose staging unchanged (strided gather needs it).
__global__ __launch_bounds__(256, 2) void attn_kernel(const u16* __restrict__ Qb,
                                                      const u16* __restrict__ Kb,
                                                      const u16* __restrict__ Vb,
                                                      u16* __restrict__ Ob) {
  __shared__ u16 Vt[128][72];
  __shared__ u16 Ps[4][32][72];
  const int bid = blockIdx.x;
  const int qb = bid & 1, h = (bid >> 1) & 15, b = bid >> 5;
  const int tid = threadIdx.x, wid = tid >> 6, lane = tid & 63;
  const int lr = lane & 15, lg = lane >> 4;
  const u16* qh = Qb + ((long)(b * NH + h)) * TT * HD;
  const u16* kh = Kb + ((long)(b * NH + h)) * TT * HD;
  const u16* vh = Vb + ((long)(b * NH + h)) * TT * HD;
  const int q0 = qb * 128 + wid * 32;

  bf16x8 qf[2][4];
#pragma unroll
  for (int fq = 0; fq < 2; ++fq)
#pragma unroll
    for (int ds = 0; ds < 4; ++ds)
      qf[fq][ds] = *(const bf16x8*)(qh + (long)(q0 + fq * 16 + lr) * HD + ds * 32 + lg * 8);

  const f32x4 zero = {0.f, 0.f, 0.f, 0.f};
  f32x4 oacc[2][8];
#pragma unroll
  for (int fq = 0; fq < 2; ++fq)
#pragma unroll
    for (int fd = 0; fd < 8; ++fd) oacc[fq][fd] = zero;
  float mrow[2][4], lrow[2][4];
#pragma unroll
  for (int fq = 0; fq < 2; ++fq)
#pragma unroll
    for (int r = 0; r < 4; ++r) { mrow[fq][r] = -1e30f; lrow[fq][r] = 0.f; }

  const int nch = (qb == 0) ? 2 : 4;
  for (int kc = 0; kc < nch; ++kc) {
    __syncthreads();
    // stage V chunk transposed (K read direct from global -- L1-broadcast)
#pragma unroll
    for (int it = 0; it < 4; ++it) {
      int task = it * 256 + tid;
      int r = task >> 4, d0 = (task & 15) * 8;
      u16x8 v = *(const u16x8*)(vh + (long)(kc * 64 + r) * HD + d0);
#pragma unroll
      for (int j = 0; j < 8; ++j) Vt[d0 + j][r] = v[j];
    }
    __syncthreads();

    f32x4 sacc[2][4];
#pragma unroll
    for (int fq = 0; fq < 2; ++fq)
#pragma unroll
      for (int fk = 0; fk < 4; ++fk) sacc[fq][fk] = zero;
#pragma unroll
    for (int ds = 0; ds < 4; ++ds) {
      bf16x8 kf[4];
#pragma unroll
      for (int fk = 0; fk < 4; ++fk)
        kf[fk] = *(const bf16x8*)(kh + (long)(kc * 64 + fk * 16 + lr) * HD + ds * 32 + lg * 8);
#pragma unroll
      for (int fq = 0; fq < 2; ++fq)
#pragma unroll
        for (int fk = 0; fk < 4; ++fk)
          sacc[fq][fk] =
              __builtin_amdgcn_mfma_f32_16x16x32_bf16(qf[fq][ds], kf[fk], sacc[fq][fk], 0, 0, 0);
    }

#pragma unroll
    for (int fq = 0; fq < 2; ++fq) {
      float mnew[4], alpha[4], psum[4];
#pragma unroll
      for (int r = 0; r < 4; ++r) {
        int qrow = q0 + fq * 16 + lg * 4 + r;
        float cmax = -1e30f;
#pragma unroll
        for (int fk = 0; fk < 4; ++fk) {
          int kcol = kc * 64 + fk * 16 + lr;
          float s = sacc[fq][fk][r];
          if (kcol > qrow) s = -1e30f;
          sacc[fq][fk][r] = s;
          cmax = fmaxf(cmax, s);
        }
#pragma unroll
        for (int off = 1; off < 16; off <<= 1) cmax = fmaxf(cmax, __shfl_xor(cmax, off));
        mnew[r] = fmaxf(mrow[fq][r], cmax);
        alpha[r] = __expf(mrow[fq][r] - mnew[r]);
        mrow[fq][r] = mnew[r];
        psum[r] = 0.f;
      }
#pragma unroll
      for (int fk = 0; fk < 4; ++fk)
#pragma unroll
        for (int r = 0; r < 4; ++r) {
          float p = __expf(sacc[fq][fk][r] - mnew[r]);
          psum[r] += p;
          Ps[wid][fq * 16 + lg * 4 + r][fk * 16 + lr] = f2bf(p);
        }
#pragma unroll
      for (int r = 0; r < 4; ++r) {
        float ps = psum[r];
#pragma unroll
        for (int off = 1; off < 16; off <<= 1) ps += __shfl_xor(ps, off);
        lrow[fq][r] = lrow[fq][r] * alpha[r] + ps;
#pragma unroll
        for (int fd = 0; fd < 8; ++fd) oacc[fq][fd][r] *= alpha[r];
      }
    }

#pragma unroll
    for (int ks = 0; ks < 2; ++ks) {
      bf16x8 pf0 = *(const bf16x8*)(&Ps[wid][lr][ks * 32 + lg * 8]);
      bf16x8 pf1 = *(const bf16x8*)(&Ps[wid][16 + lr][ks * 32 + lg * 8]);
#pragma unroll
      for (int fd = 0; fd < 8; ++fd) {
        bf16x8 vf = *(const bf16x8*)(&Vt[fd * 16 + lr][ks * 32 + lg * 8]);
        oacc[0][fd] = __builtin_amdgcn_mfma_f32_16x16x32_bf16(pf0, vf, oacc[0][fd], 0, 0, 0);
        oacc[1][fd] = __builtin_amdgcn_mfma_f32_16x16x32_bf16(pf1, vf, oacc[1][fd], 0, 0, 0);
      }
    }
  }

#pragma unroll
  for (int fq = 0; fq < 2; ++fq)
#pragma unroll
    for (int r = 0; r < 4; ++r) {
      float inv = 1.0f / lrow[fq][r];
      int t = q0 + fq * 16 + lg * 4 + r;
      u16* od = Ob + ((long)(b * TT + t)) * CDIM + h * HD;
#pragma unroll
      for (int fd = 0; fd < 8; ++fd) od[fd * 16 + lr] = f2bf(oacc[fq][fd][r] * inv);
    }
}

extern "C" void kernel_launch(void* const* d_in, const int* in_sizes, int n_in, void* d_out,
                              int out_size, void* d_ws, size_t ws_size, hipStream_t stream) {
  const float* x = (const float*)d_in[0];
  const float* wq = (const float*)d_in[2];
  const float* wk = (const float*)d_in[3];
  const float* wv = (const float*)d_in[4];
  const float* wo = (const float*)d_in[5];

  char* ws = (char*)d_ws;
  u16* xbf = (u16*)(ws);                   // 32 MB; later reused as attn-out [b][t][c]
  u16* wqkv = (u16*)(ws + 33554432);       // 24 MB  [6144][2048]
  u16* wobf = (u16*)(ws + 58720256);       // 8 MB
  u16* qbf = (u16*)(ws + 67108864);        // 32 MB  [b][h][t][d]
  u16* kbf = (u16*)(ws + 100663296);       // 32 MB
  u16* vbf = (u16*)(ws + 134217728);       // 32 MB
  float* cosT = (float*)(ws + 167772160);  // 64 KB
  float* sinT = (float*)(ws + 167837696);  // 64 KB

  cvt_bf16_kernel<<<8192, 256, 0, stream>>>(x, xbf, 2097152);
  cvt_w_kernel<<<8192, 256, 0, stream>>>(wq, wk, wv, wo, wqkv, wobf);
  rope_tables_kernel<<<64, 256, 0, stream>>>(cosT, sinT);

  gemm256<1><<<768, 512, 0, stream>>>(xbf, wqkv, nullptr, qbf, kbf, vbf, cosT, sinT, 8192, 6144,
                                      2048, 24);
  attn_kernel<<<1024, 256, 0, stream>>>(qbf, kbf, vbf, xbf);
  gemm256<0><<<256, 512, 0, stream>>>(xbf, wobf, (float*)d_out, nullptr, nullptr, nullptr, nullptr,
                                      nullptr, 8192, 2048, 2048, 8);
}

// Round 15
// 332.503 us; speedup vs baseline: 1.1472x; 1.0672x over previous
//
#include <hip/hip_runtime.h>

typedef unsigned short u16;
typedef unsigned int u32;
typedef __attribute__((ext_vector_type(4))) float f32x4;
typedef __attribute__((ext_vector_type(8))) short bf16x8;
typedef __attribute__((ext_vector_type(4))) unsigned short u16x4;
typedef __attribute__((ext_vector_type(8))) unsigned short u16x8;

#define NH 16
#define HD 128
#define TT 256
#define CDIM 2048

__device__ __forceinline__ u16 f2bf(float f) {
  u32 u = __float_as_uint(f);
  u = (u + 0x7fffu + ((u >> 16) & 1u)) >> 16;
  return (u16)u;
}
__device__ __forceinline__ float bf2f(u16 h) {
  return __uint_as_float(((u32)h) << 16);
}
__device__ __forceinline__ void gload_lds16(const u16* g, u16* l) {
  __builtin_amdgcn_global_load_lds((__attribute__((address_space(1))) void*)g,
                                   (__attribute__((address_space(3))) void*)l, 16, 0, 0);
}

#define BAR() __builtin_amdgcn_s_barrier()
#define SCB() __builtin_amdgcn_sched_barrier(0)
#define WL0()                                          \
  {                                                    \
    asm volatile("s_waitcnt lgkmcnt(0)" ::: "memory"); \
    SCB();                                             \
  }
#define WV8()                                         \
  {                                                   \
    asm volatile("s_waitcnt vmcnt(8)" ::: "memory");  \
    SCB();                                            \
  }
#define WVL0()                                                   \
  {                                                              \
    asm volatile("s_waitcnt vmcnt(0) lgkmcnt(0)" ::: "memory");  \
    SCB();                                                       \
  }
#define P1() __builtin_amdgcn_s_setprio(1)
#define P0() __builtin_amdgcn_s_setprio(0)

// ---------------- convert f32 -> bf16, 8 elems/thread ----------------
__global__ __launch_bounds__(256) void cvt_bf16_kernel(const float* __restrict__ src,
                                                       u16* __restrict__ dst, int n8) {
  int i = blockIdx.x * 256 + threadIdx.x;
  if (i >= n8) return;
  const float4* s4 = (const float4*)src;
  float4 a = s4[i * 2];
  float4 b = s4[i * 2 + 1];
  u16x8 r;
  r[0] = f2bf(a.x); r[1] = f2bf(a.y); r[2] = f2bf(a.z); r[3] = f2bf(a.w);
  r[4] = f2bf(b.x); r[5] = f2bf(b.y); r[6] = f2bf(b.z); r[7] = f2bf(b.w);
  *(u16x8*)(dst + (long)i * 8) = r;
}

// all four weight matrices in one launch
__global__ __launch_bounds__(256) void cvt_w_kernel(const float* __restrict__ wq,
                                                    const float* __restrict__ wk,
                                                    const float* __restrict__ wv,
                                                    const float* __restrict__ wo,
                                                    u16* __restrict__ wqkv,
                                                    u16* __restrict__ wobf) {
  int i = blockIdx.x * 256 + threadIdx.x;
  int seg = i >> 19;
  int r8 = i & 524287;
  const float* s = (seg == 0) ? wq : (seg == 1) ? wk : (seg == 2) ? wv : wo;
  u16* d = (seg == 3) ? wobf : (wqkv + (long)seg * 4194304);
  const float4* s4 = (const float4*)s;
  float4 a = s4[r8 * 2];
  float4 b = s4[r8 * 2 + 1];
  u16x8 r;
  r[0] = f2bf(a.x); r[1] = f2bf(a.y); r[2] = f2bf(a.z); r[3] = f2bf(a.w);
  r[4] = f2bf(b.x); r[5] = f2bf(b.y); r[6] = f2bf(b.z); r[7] = f2bf(b.w);
  *(u16x8*)(d + (long)r8 * 8) = r;
}

// ---------------- rope tables: [256][64] cos,sin ----------------
__global__ void rope_tables_kernel(float* __restrict__ cosT, float* __restrict__ sinT) {
  int i = blockIdx.x * 256 + threadIdx.x;  // 16384
  int t = i >> 6, d = i & 63;
  float inv = __expf(-(float)d * (9.210340371976184f / 64.0f));
  float a = (float)t * inv;
  cosT[i] = cosf(a);
  sinT[i] = sinf(a);
}

// ---------------- 256x256 GEMM  C = A * B^T (R12/R7 structure, frozen) ----------------
#define LDA_(CB)                                                     \
  _Pragma("unroll") for (int f = 0; f < 4; ++f)                      \
  _Pragma("unroll") for (int ks = 0; ks < 2; ++ks)                   \
      fa[f][ks] = *(const bf16x8*)&lds[(CB) + wr64 + f * 1024 + lb[ks]];

#define LDB_(CB, Q)                                                  \
  _Pragma("unroll") for (int fn = 0; fn < 2; ++fn)                   \
  _Pragma("unroll") for (int ks = 0; ks < 2; ++ks)                   \
      fb[fn][ks] = *(const bf16x8*)&lds[(CB) + wbB + (Q)*2048 + fn * 1024 + lb[ks]];

#define MMQ(Q)                                                       \
  _Pragma("unroll") for (int ks = 0; ks < 2; ++ks)                   \
  _Pragma("unroll") for (int f = 0; f < 4; ++f)                      \
  _Pragma("unroll") for (int fn = 0; fn < 2; ++fn)                   \
      acc[f][(Q)*2 + fn] = __builtin_amdgcn_mfma_f32_16x16x32_bf16(  \
          fa[f][ks], fb[fn][ks], acc[f][(Q)*2 + fn], 0, 0, 0);

template <int MODE>
__global__ __launch_bounds__(512, 2) void gemm256(const u16* __restrict__ A,
                                                  const u16* __restrict__ Bt,
                                                  float* __restrict__ Cf, u16* __restrict__ Qo,
                                                  u16* __restrict__ Ko, u16* __restrict__ Vo,
                                                  const float* __restrict__ cosT,
                                                  const float* __restrict__ sinT,
                                                  int M, int N, int K, int GX) {
  __shared__ u16 lds[65536];  // buf c at c*32768: [A 4x4096][B 4x4096] u16
  const int wg = blockIdx.x;
  const int bn = wg % GX, bm = wg / GX;
  const int tid = threadIdx.x, wid = tid >> 6, lane = tid & 63;
  const int lr = lane & 15, lg = lane >> 4;
  const int wr = (wid >> 1) * 64;      // wave A-row base in [0,256)
  const int wch = wid & 1;             // wave B-half (C cols wch*128 .. +127)
  const int wr64 = (wid >> 1) * 4096;  // hoisted A base
  const int wbB = 16384 + wch * 8192;  // hoisted B base
  const int NT = K >> 6;
  const long KU = (long)64 * K;
  const u16* Ag = A + (long)(bm * 256) * K;
  const u16* Bg = Bt + (long)(bn * 256) * K;

  int lb[2];
#pragma unroll
  for (int ks = 0; ks < 2; ++ks) lb[ks] = lr * 64 + (((ks * 4 + lg) ^ (lr & 7))) * 8;

  const int csg = ((tid & 7) ^ ((tid >> 3) & 7)) * 8;
  const u16* aBase = Ag + (long)(tid >> 3) * K + csg;
  const u16* bBase = Bg + (long)(tid >> 3) * K + csg;
  auto STGA = [&](int ldso, int u, int kt) {
    if (kt > NT - 1) kt = NT - 1;
    gload_lds16(aBase + (long)u * KU + kt * 64, &lds[ldso + tid * 8]);
  };
  auto STGB = [&](int ldso, int u, int kt) {
    if (kt > NT - 1) kt = NT - 1;
    gload_lds16(bBase + (long)u * KU + kt * 64, &lds[ldso + tid * 8]);
  };

  bf16x8 fa[4][2], fb[2][2];
  const f32x4 zero = {0.f, 0.f, 0.f, 0.f};
  f32x4 acc[4][8];
#pragma unroll
  for (int a = 0; a < 4; ++a)
#pragma unroll
    for (int b = 0; b < 8; ++b) acc[a][b] = zero;

  STGA(0, 0, 0);
  STGA(4096, 1, 0);
  STGA(8192, 2, 0);
  STGA(12288, 3, 0);
  STGB(16384, 0, 0);
  STGB(24576, 2, 0);
  STGB(20480, 1, 0);
  STGB(28672, 3, 0);
  STGA(32768, 0, 1);
  STGA(36864, 1, 1);
  STGA(40960, 2, 1);
  STGA(45056, 3, 1);
  STGB(49152, 0, 1);
  STGB(57344, 2, 1);
  WV8();
  BAR();

#define TILE(CB, OB, T1, T2)       \
  LDA_(CB)                         \
  LDB_(CB, 0)                      \
  STGB((OB) + 20480, 1, T1);       \
  STGB((OB) + 28672, 3, T1);       \
  BAR(); WL0();                    \
  P1(); MMQ(0) P0();               \
  BAR();                           \
  LDB_(CB, 1)                      \
  STGA((CB) + 0, 0, T2);           \
  STGA((CB) + 4096, 1, T2);        \
  BAR(); WL0();                    \
  P1(); MMQ(1) P0();               \
  WV8();                           \
  BAR();                           \
  LDB_(CB, 2)                      \
  STGA((CB) + 8192, 2, T2);        \
  STGA((CB) + 12288, 3, T2);       \
  BAR(); WL0();                    \
  P1(); MMQ(2) P0();               \
  BAR();                           \
  LDB_(CB, 3)                      \
  STGB((CB) + 16384, 0, T2);       \
  STGB((CB) + 24576, 2, T2);       \
  BAR(); WL0();                    \
  P1(); MMQ(3) P0();               \
  WV8();                           \
  BAR();

  const int J = NT >> 1;
  for (int j = 0; j < J; ++j) {
    const int t1 = 2 * j + 1, t2 = 2 * j + 2, t3 = 2 * j + 3;
    TILE(0, 32768, t1, t2)
    TILE(32768, 0, t2, t3)
  }
  WVL0();
  BAR();

  if (MODE == 0) {
#pragma unroll
    for (int f = 0; f < 4; ++f)
#pragma unroll
      for (int j8 = 0; j8 < 8; ++j8)
#pragma unroll
        for (int r = 0; r < 4; ++r) {
          int m = bm * 256 + wr + f * 16 + lg * 4 + r;
          int n = bn * 256 + wch * 128 + (j8 >> 1) * 32 + (j8 & 1) * 16 + lr;
          Cf[(long)m * N + n] = acc[f][j8][r];
        }
  } else {
    const int mat = bn >> 3;
    u16* dst = (mat == 0) ? Qo : ((mat == 1) ? Ko : Vo);
    const float qsc = (mat == 0) ? 0.08838834764831845f : 1.0f;
#pragma unroll
    for (int mh = 0; mh < 2; ++mh) {
      if (mh) BAR();
      if ((wid >> 2) == mh) {
#pragma unroll
        for (int f = 0; f < 4; ++f)
#pragma unroll
          for (int j8 = 0; j8 < 8; ++j8)
#pragma unroll
            for (int r = 0; r < 4; ++r) {
              int rowl = ((wid >> 1) & 1) * 64 + f * 16 + lg * 4 + r;
              int col = wch * 128 + (j8 >> 1) * 32 + (j8 & 1) * 16 + lr;
              lds[rowl * 272 + col] = f2bf(acc[f][j8][r]);
            }
      }
      BAR();
#pragma unroll
      for (int it = 0; it < 8; ++it) {
        int task = it * 512 + tid;
        int tl = task >> 5, c8 = task & 31;
        int hp = c8 >> 4, d0 = (c8 & 15) * 8;
        int t = mh * 128 + tl;
        int head = (bn * 2 + hp) & 15;
        u16x8 v1 = *(const u16x8*)&lds[tl * 272 + hp * 128 + d0];
        u16x8 o;
        if (mat < 2) {
          int dpart = (d0 < 64) ? (d0 + 64) : (d0 - 64);
          u16x8 v2 = *(const u16x8*)&lds[tl * 272 + hp * 128 + dpart];
          int dm = d0 & 63;
          float4 c0 = *(const float4*)(cosT + t * 64 + dm);
          float4 c1 = *(const float4*)(cosT + t * 64 + dm + 4);
          float4 s0 = *(const float4*)(sinT + t * 64 + dm);
          float4 s1 = *(const float4*)(sinT + t * 64 + dm + 4);
          float cc[8] = {c0.x, c0.y, c0.z, c0.w, c1.x, c1.y, c1.z, c1.w};
          float ss[8] = {s0.x, s0.y, s0.z, s0.w, s1.x, s1.y, s1.z, s1.w};
          float sgn = (d0 < 64) ? -1.f : 1.f;
#pragma unroll
          for (int jj = 0; jj < 8; ++jj)
            o[jj] = f2bf((bf2f(v1[jj]) * cc[jj] + sgn * bf2f(v2[jj]) * ss[jj]) * qsc);
        } else {
          o = v1;
        }
        *(u16x8*)(dst + (((long)(bm * NH + head)) * TT + t) * HD + d0) = o;
      }
    }
  }
}

// ---------------- fused causal attention ----------------
// R15: R12 data path verbatim (staged K row-major +8 pad, padded V-transpose,
// Ps per-wave) -- the measured-best combination. ONE orthogonal change:
// heavy-first block ordering (bids 0..511 = qb=1 blocks with 4 K-chunks,
// 512..1023 = qb=0 with 2) so the light blocks fill the scheduling tail.
__global__ __launch_bounds__(256, 2) void attn_kernel(const u16* __restrict__ Qb,
                                                      const u16* __restrict__ Kb,
                                                      const u16* __restrict__ Vb,
                                                      u16* __restrict__ Ob) {
  __shared__ u16 Ks[64][136];
  __shared__ u16 Vt[128][72];
  __shared__ u16 Ps[4][32][72];
  const int bid = blockIdx.x;
  const int qb = (bid < 512) ? 1 : 0;
  const int hb = (bid < 512) ? bid : (bid - 512);
  const int h = hb & 15, b = hb >> 4;
  const int tid = threadIdx.x, wid = tid >> 6, lane = tid & 63;
  const int lr = lane & 15, lg = lane >> 4;
  const u16* qh = Qb + ((long)(b * NH + h)) * TT * HD;
  const u16* kh = Kb + ((long)(b * NH + h)) * TT * HD;
  const u16* vh = Vb + ((long)(b * NH + h)) * TT * HD;
  const int q0 = qb * 128 + wid * 32;

  bf16x8 qf[2][4];
#pragma unroll
  for (int fq = 0; fq < 2; ++fq)
#pragma unroll
    for (int ds = 0; ds < 4; ++ds)
      qf[fq][ds] = *(const bf16x8*)(qh + (long)(q0 + fq * 16 + lr) * HD + ds * 32 + lg * 8);

  const f32x4 zero = {0.f, 0.f, 0.f, 0.f};
  f32x4 oacc[2][8];
#pragma unroll
  for (int fq = 0; fq < 2; ++fq)
#pragma unroll
    for (int fd = 0; fd < 8; ++fd) oacc[fq][fd] = zero;
  float mrow[2][4], lrow[2][4];
#pragma unroll
  for (int fq = 0; fq < 2; ++fq)
#pragma unroll
    for (int r = 0; r < 4; ++r) { mrow[fq][r] = -1e30f; lrow[fq][r] = 0.f; }

  const int nch = (qb == 0) ? 2 : 4;
  for (int kc = 0; kc < nch; ++kc) {
    __syncthreads();
#pragma unroll
    for (int it = 0; it < 4; ++it) {
      int task = it * 256 + tid;
      int r = task >> 4, sg = task & 15;
      u16x8 v = *(const u16x8*)(kh + (long)(kc * 64 + r) * HD + sg * 8);
      *(u16x8*)(&Ks[r][sg * 8]) = v;
    }
#pragma unroll
    for (int it = 0; it < 4; ++it) {
      int task = it * 256 + tid;
      int r = task >> 4, d0 = (task & 15) * 8;
      u16x8 v = *(const u16x8*)(vh + (long)(kc * 64 + r) * HD + d0);
#pragma unroll
      for (int j = 0; j < 8; ++j) Vt[d0 + j][r] = v[j];
    }
    __syncthreads();

    f32x4 sacc[2][4];
#pragma unroll
    for (int fq = 0; fq < 2; ++fq)
#pragma unroll
      for (int fk = 0; fk < 4; ++fk) sacc[fq][fk] = zero;
#pragma unroll
    for (int ds = 0; ds < 4; ++ds) {
      bf16x8 kf[4];
#pragma unroll
      for (int fk = 0; fk < 4; ++fk)
        kf[fk] = *(const bf16x8*)(&Ks[fk * 16 + lr][ds * 32 + lg * 8]);
#pragma unroll
      for (int fq = 0; fq < 2; ++fq)
#pragma unroll
        for (int fk = 0; fk < 4; ++fk)
          sacc[fq][fk] =
              __builtin_amdgcn_mfma_f32_16x16x32_bf16(qf[fq][ds], kf[fk], sacc[fq][fk], 0, 0, 0);
    }

#pragma unroll
    for (int fq = 0; fq < 2; ++fq) {
      float mnew[4], alpha[4], psum[4];
#pragma unroll
      for (int r = 0; r < 4; ++r) {
        int qrow = q0 + fq * 16 + lg * 4 + r;
        float cmax = -1e30f;
#pragma unroll
        for (int fk = 0; fk < 4; ++fk) {
          int kcol = kc * 64 + fk * 16 + lr;
          float s = sacc[fq][fk][r];
          if (kcol > qrow) s = -1e30f;
          sacc[fq][fk][r] = s;
          cmax = fmaxf(cmax, s);
        }
#pragma unroll
        for (int off = 1; off < 16; off <<= 1) cmax = fmaxf(cmax, __shfl_xor(cmax, off));
        mnew[r] = fmaxf(mrow[fq][r], cmax);
        alpha[r] = __expf(mrow[fq][r] - mnew[r]);
        mrow[fq][r] = mnew[r];
        psum[r] = 0.f;
      }
#pragma unroll
      for (int fk = 0; fk < 4; ++fk)
#pragma unroll
        for (int r = 0; r < 4; ++r) {
          float p = __expf(sacc[fq][fk][r] - mnew[r]);
          psum[r] += p;
          Ps[wid][fq * 16 + lg * 4 + r][fk * 16 + lr] = f2bf(p);
        }
#pragma unroll
      for (int r = 0; r < 4; ++r) {
        float ps = psum[r];
#pragma unroll
        for (int off = 1; off < 16; off <<= 1) ps += __shfl_xor(ps, off);
        lrow[fq][r] = lrow[fq][r] * alpha[r] + ps;
#pragma unroll
        for (int fd = 0; fd < 8; ++fd) oacc[fq][fd][r] *= alpha[r];
      }
    }

#pragma unroll
    for (int ks = 0; ks < 2; ++ks) {
      bf16x8 pf0 = *(const bf16x8*)(&Ps[wid][lr][ks * 32 + lg * 8]);
      bf16x8 pf1 = *(const bf16x8*)(&Ps[wid][16 + lr][ks * 32 + lg * 8]);
#pragma unroll
      for (int fd = 0; fd < 8; ++fd) {
        bf16x8 vf = *(const bf16x8*)(&Vt[fd * 16 + lr][ks * 32 + lg * 8]);
        oacc[0][fd] = __builtin_amdgcn_mfma_f32_16x16x32_bf16(pf0, vf, oacc[0][fd], 0, 0, 0);
        oacc[1][fd] = __builtin_amdgcn_mfma_f32_16x16x32_bf16(pf1, vf, oacc[1][fd], 0, 0, 0);
      }
    }
  }

#pragma unroll
  for (int fq = 0; fq < 2; ++fq)
#pragma unroll
    for (int r = 0; r < 4; ++r) {
      float inv = 1.0f / lrow[fq][r];
      int t = q0 + fq * 16 + lg * 4 + r;
      u16* od = Ob + ((long)(b * TT + t)) * CDIM + h * HD;
#pragma unroll
      for (int fd = 0; fd < 8; ++fd) od[fd * 16 + lr] = f2bf(oacc[fq][fd][r] * inv);
    }
}

extern "C" void kernel_launch(void* const* d_in, const int* in_sizes, int n_in, void* d_out,
                              int out_size, void* d_ws, size_t ws_size, hipStream_t stream) {
  const float* x = (const float*)d_in[0];
  const float* wq = (const float*)d_in[2];
  const float* wk = (const float*)d_in[3];
  const float* wv = (const float*)d_in[4];
  const float* wo = (const float*)d_in[5];

  char* ws = (char*)d_ws;
  u16* xbf = (u16*)(ws);                   // 32 MB; later reused as attn-out [b][t][c]
  u16* wqkv = (u16*)(ws + 33554432);       // 24 MB  [6144][2048]
  u16* wobf = (u16*)(ws + 58720256);       // 8 MB
  u16* qbf = (u16*)(ws + 67108864);        // 32 MB  [b][h][t][d]
  u16* kbf = (u16*)(ws + 100663296);       // 32 MB
  u16* vbf = (u16*)(ws + 134217728);       // 32 MB
  float* cosT = (float*)(ws + 167772160);  // 64 KB
  float* sinT = (float*)(ws + 167837696);  // 64 KB

  cvt_bf16_kernel<<<8192, 256, 0, stream>>>(x, xbf, 2097152);
  cvt_w_kernel<<<8192, 256, 0, stream>>>(wq, wk, wv, wo, wqkv, wobf);
  rope_tables_kernel<<<64, 256, 0, stream>>>(cosT, sinT);

  gemm256<1><<<768, 512, 0, stream>>>(xbf, wqkv, nullptr, qbf, kbf, vbf, cosT, sinT, 8192, 6144,
                                      2048, 24);
  attn_kernel<<<1024, 256, 0, stream>>>(qbf, kbf, vbf, xbf);
  gemm256<0><<<256, 512, 0, stream>>>(xbf, wobf, (float*)d_out, nullptr, nullptr, nullptr, nullptr,
                                      nullptr, 8192, 2048, 2048, 8);
}

// Round 16
// 329.505 us; speedup vs baseline: 1.1576x; 1.0091x over previous
//
#include <hip/hip_runtime.h>

typedef unsigned short u16;
typedef unsigned int u32;
typedef __attribute__((ext_vector_type(4))) float f32x4;
typedef __attribute__((ext_vector_type(8))) short bf16x8;
typedef __attribute__((ext_vector_type(4))) unsigned short u16x4;
typedef __attribute__((ext_vector_type(8))) unsigned short u16x8;

#define NH 16
#define HD 128
#define TT 256
#define CDIM 2048

__device__ __forceinline__ u16 f2bf(float f) {
  u32 u = __float_as_uint(f);
  u = (u + 0x7fffu + ((u >> 16) & 1u)) >> 16;
  return (u16)u;
}
__device__ __forceinline__ float bf2f(u16 h) {
  return __uint_as_float(((u32)h) << 16);
}
__device__ __forceinline__ void gload_lds16(const u16* g, u16* l) {
  __builtin_amdgcn_global_load_lds((__attribute__((address_space(1))) void*)g,
                                   (__attribute__((address_space(3))) void*)l, 16, 0, 0);
}

#define BAR() __builtin_amdgcn_s_barrier()
#define SCB() __builtin_amdgcn_sched_barrier(0)
#define WL0()                                          \
  {                                                    \
    asm volatile("s_waitcnt lgkmcnt(0)" ::: "memory"); \
    SCB();                                             \
  }
#define WV6()                                         \
  {                                                   \
    asm volatile("s_waitcnt vmcnt(6)" ::: "memory");  \
    SCB();                                            \
  }
#define WV8()                                         \
  {                                                   \
    asm volatile("s_waitcnt vmcnt(8)" ::: "memory");  \
    SCB();                                            \
  }
#define WVL0()                                                   \
  {                                                              \
    asm volatile("s_waitcnt vmcnt(0) lgkmcnt(0)" ::: "memory");  \
    SCB();                                                       \
  }
#define P1() __builtin_amdgcn_s_setprio(1)
#define P0() __builtin_amdgcn_s_setprio(0)

// ---------------- convert f32 -> bf16, 8 elems/thread ----------------
__global__ __launch_bounds__(256) void cvt_bf16_kernel(const float* __restrict__ src,
                                                       u16* __restrict__ dst, int n8) {
  int i = blockIdx.x * 256 + threadIdx.x;
  if (i >= n8) return;
  const float4* s4 = (const float4*)src;
  float4 a = s4[i * 2];
  float4 b = s4[i * 2 + 1];
  u16x8 r;
  r[0] = f2bf(a.x); r[1] = f2bf(a.y); r[2] = f2bf(a.z); r[3] = f2bf(a.w);
  r[4] = f2bf(b.x); r[5] = f2bf(b.y); r[6] = f2bf(b.z); r[7] = f2bf(b.w);
  *(u16x8*)(dst + (long)i * 8) = r;
}

// all four weight matrices in one launch
__global__ __launch_bounds__(256) void cvt_w_kernel(const float* __restrict__ wq,
                                                    const float* __restrict__ wk,
                                                    const float* __restrict__ wv,
                                                    const float* __restrict__ wo,
                                                    u16* __restrict__ wqkv,
                                                    u16* __restrict__ wobf) {
  int i = blockIdx.x * 256 + threadIdx.x;
  int seg = i >> 19;
  int r8 = i & 524287;
  const float* s = (seg == 0) ? wq : (seg == 1) ? wk : (seg == 2) ? wv : wo;
  u16* d = (seg == 3) ? wobf : (wqkv + (long)seg * 4194304);
  const float4* s4 = (const float4*)s;
  float4 a = s4[r8 * 2];
  float4 b = s4[r8 * 2 + 1];
  u16x8 r;
  r[0] = f2bf(a.x); r[1] = f2bf(a.y); r[2] = f2bf(a.z); r[3] = f2bf(a.w);
  r[4] = f2bf(b.x); r[5] = f2bf(b.y); r[6] = f2bf(b.z); r[7] = f2bf(b.w);
  *(u16x8*)(d + (long)r8 * 8) = r;
}

// ---------------- rope tables: [256][64] cos,sin ----------------
__global__ void rope_tables_kernel(float* __restrict__ cosT, float* __restrict__ sinT) {
  int i = blockIdx.x * 256 + threadIdx.x;  // 16384
  int t = i >> 6, d = i & 63;
  float inv = __expf(-(float)d * (9.210340371976184f / 64.0f));
  float a = (float)t * inv;
  cosT[i] = cosf(a);
  sinT[i] = sinf(a);
}

// ---------------- 256x256 GEMM  C = A * B^T ----------------
// R16: R7/R12 rotation at 2-phases-per-K-tile with ONE barrier per phase.
// Write-safety chain: reads of region R -> each wave's WL0 -> single BAR ->
// stage into R (next phase). vmcnt ledger (derived, prologue traced):
// phase A ends WV6 (drains t-1.A's 2 ops before phase B reads CB.Bu1u3);
// phase B ends WV8 (drains t-1.B's 6 ops before t+1.A reads CB'.A+Bu0u2).
// Sync per K-tile: 2 BAR + 2 lgkm + 2 vm (was 8+4+2 in R7/R12).
#define LDA_(CB)                                                     \
  _Pragma("unroll") for (int f = 0; f < 4; ++f)                      \
  _Pragma("unroll") for (int ks = 0; ks < 2; ++ks)                   \
      fa[f][ks] = *(const bf16x8*)&lds[(CB) + wr64 + f * 1024 + lb[ks]];

#define LDB_(FB, CB, Q)                                              \
  _Pragma("unroll") for (int fn = 0; fn < 2; ++fn)                   \
  _Pragma("unroll") for (int ks = 0; ks < 2; ++ks)                   \
      FB[fn][ks] = *(const bf16x8*)&lds[(CB) + wbB + (Q)*2048 + fn * 1024 + lb[ks]];

#define MMQ(FB, Q)                                                   \
  _Pragma("unroll") for (int ks = 0; ks < 2; ++ks)                   \
  _Pragma("unroll") for (int f = 0; f < 4; ++f)                      \
  _Pragma("unroll") for (int fn = 0; fn < 2; ++fn)                   \
      acc[f][(Q)*2 + fn] = __builtin_amdgcn_mfma_f32_16x16x32_bf16(  \
          fa[f][ks], FB[fn][ks], acc[f][(Q)*2 + fn], 0, 0, 0);

template <int MODE>
__global__ __launch_bounds__(512, 2) void gemm256(const u16* __restrict__ A,
                                                  const u16* __restrict__ Bt,
                                                  float* __restrict__ Cf, u16* __restrict__ Qo,
                                                  u16* __restrict__ Ko, u16* __restrict__ Vo,
                                                  const float* __restrict__ cosT,
                                                  const float* __restrict__ sinT,
                                                  int M, int N, int K, int GX) {
  __shared__ u16 lds[65536];  // buf c at c*32768: [A 4x4096][B 4x4096] u16
  const int wg = blockIdx.x;
  const int bn = wg % GX, bm = wg / GX;
  const int tid = threadIdx.x, wid = tid >> 6, lane = tid & 63;
  const int lr = lane & 15, lg = lane >> 4;
  const int wr = (wid >> 1) * 64;      // wave A-row base in [0,256)
  const int wch = wid & 1;             // wave B-half (C cols wch*128 .. +127)
  const int wr64 = (wid >> 1) * 4096;  // hoisted A base
  const int wbB = 16384 + wch * 8192;  // hoisted B base
  const int NT = K >> 6;
  const long KU = (long)64 * K;
  const u16* Ag = A + (long)(bm * 256) * K;
  const u16* Bg = Bt + (long)(bn * 256) * K;

  int lb[2];
#pragma unroll
  for (int ks = 0; ks < 2; ++ks) lb[ks] = lr * 64 + (((ks * 4 + lg) ^ (lr & 7))) * 8;

  const int csg = ((tid & 7) ^ ((tid >> 3) & 7)) * 8;
  const u16* aBase = Ag + (long)(tid >> 3) * K + csg;
  const u16* bBase = Bg + (long)(tid >> 3) * K + csg;
  auto STGA = [&](int ldso, int u, int kt) {
    if (kt > NT - 1) kt = NT - 1;
    gload_lds16(aBase + (long)u * KU + kt * 64, &lds[ldso + tid * 8]);
  };
  auto STGB = [&](int ldso, int u, int kt) {
    if (kt > NT - 1) kt = NT - 1;
    gload_lds16(bBase + (long)u * KU + kt * 64, &lds[ldso + tid * 8]);
  };

  bf16x8 fa[4][2], fbA[2][2], fbB[2][2];
  const f32x4 zero = {0.f, 0.f, 0.f, 0.f};
  f32x4 acc[4][8];
#pragma unroll
  for (int a = 0; a < 4; ++a)
#pragma unroll
    for (int b = 0; b < 8; ++b) acc[a][b] = zero;

  // prologue: buf0 fully (A0-3, Bu0, Bu2, Bu1, Bu3) then buf1 partial (A0-3, Bu0, Bu2)
  STGA(0, 0, 0);
  STGA(4096, 1, 0);
  STGA(8192, 2, 0);
  STGA(12288, 3, 0);
  STGB(16384, 0, 0);
  STGB(24576, 2, 0);
  STGB(20480, 1, 0);
  STGB(28672, 3, 0);
  STGA(32768, 0, 1);
  STGA(36864, 1, 1);
  STGA(40960, 2, 1);
  STGA(45056, 3, 1);
  STGB(49152, 0, 1);
  STGB(57344, 2, 1);
  WV6();  // drain all 8 buf0 ops; buf1's 6 stay in flight
  BAR();

#define TILE2(CB, OB, T1, T2)      \
  LDA_(CB)                         \
  LDB_(fbA, CB, 0)                 \
  LDB_(fbB, CB, 1)                 \
  STGB((OB) + 20480, 1, T1);       \
  STGB((OB) + 28672, 3, T1);       \
  WL0();                           \
  P1(); MMQ(fbA, 0) MMQ(fbB, 1) P0(); \
  WV6();                           \
  BAR();                           \
  LDB_(fbA, CB, 2)                 \
  LDB_(fbB, CB, 3)                 \
  STGA((CB) + 0, 0, T2);           \
  STGA((CB) + 4096, 1, T2);        \
  STGA((CB) + 8192, 2, T2);        \
  STGA((CB) + 12288, 3, T2);       \
  STGB((CB) + 16384, 0, T2);       \
  STGB((CB) + 24576, 2, T2);       \
  WL0();                           \
  P1(); MMQ(fbA, 2) MMQ(fbB, 3) P0(); \
  WV8();                           \
  BAR();

  const int J = NT >> 1;
  for (int j = 0; j < J; ++j) {
    const int t1 = 2 * j + 1, t2 = 2 * j + 2, t3 = 2 * j + 3;
    TILE2(0, 32768, t1, t2)
    TILE2(32768, 0, t2, t3)
  }
  WVL0();
  BAR();

  if (MODE == 0) {
#pragma unroll
    for (int f = 0; f < 4; ++f)
#pragma unroll
      for (int j8 = 0; j8 < 8; ++j8)
#pragma unroll
        for (int r = 0; r < 4; ++r) {
          int m = bm * 256 + wr + f * 16 + lg * 4 + r;
          int n = bn * 256 + wch * 128 + (j8 >> 1) * 32 + (j8 & 1) * 16 + lr;
          Cf[(long)m * N + n] = acc[f][j8][r];
        }
  } else {
    const int mat = bn >> 3;
    u16* dst = (mat == 0) ? Qo : ((mat == 1) ? Ko : Vo);
    const float qsc = (mat == 0) ? 0.08838834764831845f : 1.0f;
#pragma unroll
    for (int mh = 0; mh < 2; ++mh) {
      if (mh) BAR();
      if ((wid >> 2) == mh) {
#pragma unroll
        for (int f = 0; f < 4; ++f)
#pragma unroll
          for (int j8 = 0; j8 < 8; ++j8)
#pragma unroll
            for (int r = 0; r < 4; ++r) {
              int rowl = ((wid >> 1) & 1) * 64 + f * 16 + lg * 4 + r;
              int col = wch * 128 + (j8 >> 1) * 32 + (j8 & 1) * 16 + lr;
              lds[rowl * 272 + col] = f2bf(acc[f][j8][r]);
            }
      }
      BAR();
#pragma unroll
      for (int it = 0; it < 8; ++it) {
        int task = it * 512 + tid;
        int tl = task >> 5, c8 = task & 31;
        int hp = c8 >> 4, d0 = (c8 & 15) * 8;
        int t = mh * 128 + tl;
        int head = (bn * 2 + hp) & 15;
        u16x8 v1 = *(const u16x8*)&lds[tl * 272 + hp * 128 + d0];
        u16x8 o;
        if (mat < 2) {
          int dpart = (d0 < 64) ? (d0 + 64) : (d0 - 64);
          u16x8 v2 = *(const u16x8*)&lds[tl * 272 + hp * 128 + dpart];
          int dm = d0 & 63;
          float4 c0 = *(const float4*)(cosT + t * 64 + dm);
          float4 c1 = *(const float4*)(cosT + t * 64 + dm + 4);
          float4 s0 = *(const float4*)(sinT + t * 64 + dm);
          float4 s1 = *(const float4*)(sinT + t * 64 + dm + 4);
          float cc[8] = {c0.x, c0.y, c0.z, c0.w, c1.x, c1.y, c1.z, c1.w};
          float ss[8] = {s0.x, s0.y, s0.z, s0.w, s1.x, s1.y, s1.z, s1.w};
          float sgn = (d0 < 64) ? -1.f : 1.f;
#pragma unroll
          for (int jj = 0; jj < 8; ++jj)
            o[jj] = f2bf((bf2f(v1[jj]) * cc[jj] + sgn * bf2f(v2[jj]) * ss[jj]) * qsc);
        } else {
          o = v1;
        }
        *(u16x8*)(dst + (((long)(bm * NH + head)) * TT + t) * HD + d0) = o;
      }
    }
  }
}

// ---------------- fused causal attention (R15, frozen) ----------------
__global__ __launch_bounds__(256, 2) void attn_kernel(const u16* __restrict__ Qb,
                                                      const u16* __restrict__ Kb,
                                                      const u16* __restrict__ Vb,
                                                      u16* __restrict__ Ob) {
  __shared__ u16 Ks[64][136];
  __shared__ u16 Vt[128][72];
  __shared__ u16 Ps[4][32][72];
  const int bid = blockIdx.x;
  const int qb = (bid < 512) ? 1 : 0;
  const int hb = (bid < 512) ? bid : (bid - 512);
  const int h = hb & 15, b = hb >> 4;
  const int tid = threadIdx.x, wid = tid >> 6, lane = tid & 63;
  const int lr = lane & 15, lg = lane >> 4;
  const u16* qh = Qb + ((long)(b * NH + h)) * TT * HD;
  const u16* kh = Kb + ((long)(b * NH + h)) * TT * HD;
  const u16* vh = Vb + ((long)(b * NH + h)) * TT * HD;
  const int q0 = qb * 128 + wid * 32;

  bf16x8 qf[2][4];
#pragma unroll
  for (int fq = 0; fq < 2; ++fq)
#pragma unroll
    for (int ds = 0; ds < 4; ++ds)
      qf[fq][ds] = *(const bf16x8*)(qh + (long)(q0 + fq * 16 + lr) * HD + ds * 32 + lg * 8);

  const f32x4 zero = {0.f, 0.f, 0.f, 0.f};
  f32x4 oacc[2][8];
#pragma unroll
  for (int fq = 0; fq < 2; ++fq)
#pragma unroll
    for (int fd = 0; fd < 8; ++fd) oacc[fq][fd] = zero;
  float mrow[2][4], lrow[2][4];
#pragma unroll
  for (int fq = 0; fq < 2; ++fq)
#pragma unroll
    for (int r = 0; r < 4; ++r) { mrow[fq][r] = -1e30f; lrow[fq][r] = 0.f; }

  const int nch = (qb == 0) ? 2 : 4;
  for (int kc = 0; kc < nch; ++kc) {
    __syncthreads();
#pragma unroll
    for (int it = 0; it < 4; ++it) {
      int task = it * 256 + tid;
      int r = task >> 4, sg = task & 15;
      u16x8 v = *(const u16x8*)(kh + (long)(kc * 64 + r) * HD + sg * 8);
      *(u16x8*)(&Ks[r][sg * 8]) = v;
    }
#pragma unroll
    for (int it = 0; it < 4; ++it) {
      int task = it * 256 + tid;
      int r = task >> 4, d0 = (task & 15) * 8;
      u16x8 v = *(const u16x8*)(vh + (long)(kc * 64 + r) * HD + d0);
#pragma unroll
      for (int j = 0; j < 8; ++j) Vt[d0 + j][r] = v[j];
    }
    __syncthreads();

    f32x4 sacc[2][4];
#pragma unroll
    for (int fq = 0; fq < 2; ++fq)
#pragma unroll
      for (int fk = 0; fk < 4; ++fk) sacc[fq][fk] = zero;
#pragma unroll
    for (int ds = 0; ds < 4; ++ds) {
      bf16x8 kf[4];
#pragma unroll
      for (int fk = 0; fk < 4; ++fk)
        kf[fk] = *(const bf16x8*)(&Ks[fk * 16 + lr][ds * 32 + lg * 8]);
#pragma unroll
      for (int fq = 0; fq < 2; ++fq)
#pragma unroll
        for (int fk = 0; fk < 4; ++fk)
          sacc[fq][fk] =
              __builtin_amdgcn_mfma_f32_16x16x32_bf16(qf[fq][ds], kf[fk], sacc[fq][fk], 0, 0, 0);
    }

#pragma unroll
    for (int fq = 0; fq < 2; ++fq) {
      float mnew[4], alpha[4], psum[4];
#pragma unroll
      for (int r = 0; r < 4; ++r) {
        int qrow = q0 + fq * 16 + lg * 4 + r;
        float cmax = -1e30f;
#pragma unroll
        for (int fk = 0; fk < 4; ++fk) {
          int kcol = kc * 64 + fk * 16 + lr;
          float s = sacc[fq][fk][r];
          if (kcol > qrow) s = -1e30f;
          sacc[fq][fk][r] = s;
          cmax = fmaxf(cmax, s);
        }
#pragma unroll
        for (int off = 1; off < 16; off <<= 1) cmax = fmaxf(cmax, __shfl_xor(cmax, off));
        mnew[r] = fmaxf(mrow[fq][r], cmax);
        alpha[r] = __expf(mrow[fq][r] - mnew[r]);
        mrow[fq][r] = mnew[r];
        psum[r] = 0.f;
      }
#pragma unroll
      for (int fk = 0; fk < 4; ++fk)
#pragma unroll
        for (int r = 0; r < 4; ++r) {
          float p = __expf(sacc[fq][fk][r] - mnew[r]);
          psum[r] += p;
          Ps[wid][fq * 16 + lg * 4 + r][fk * 16 + lr] = f2bf(p);
        }
#pragma unroll
      for (int r = 0; r < 4; ++r) {
        float ps = psum[r];
#pragma unroll
        for (int off = 1; off < 16; off <<= 1) ps += __shfl_xor(ps, off);
        lrow[fq][r] = lrow[fq][r] * alpha[r] + ps;
#pragma unroll
        for (int fd = 0; fd < 8; ++fd) oacc[fq][fd][r] *= alpha[r];
      }
    }

#pragma unroll
    for (int ks = 0; ks < 2; ++ks) {
      bf16x8 pf0 = *(const bf16x8*)(&Ps[wid][lr][ks * 32 + lg * 8]);
      bf16x8 pf1 = *(const bf16x8*)(&Ps[wid][16 + lr][ks * 32 + lg * 8]);
#pragma unroll
      for (int fd = 0; fd < 8; ++fd) {
        bf16x8 vf = *(const bf16x8*)(&Vt[fd * 16 + lr][ks * 32 + lg * 8]);
        oacc[0][fd] = __builtin_amdgcn_mfma_f32_16x16x32_bf16(pf0, vf, oacc[0][fd], 0, 0, 0);
        oacc[1][fd] = __builtin_amdgcn_mfma_f32_16x16x32_bf16(pf1, vf, oacc[1][fd], 0, 0, 0);
      }
    }
  }

#pragma unroll
  for (int fq = 0; fq < 2; ++fq)
#pragma unroll
    for (int r = 0; r < 4; ++r) {
      float inv = 1.0f / lrow[fq][r];
      int t = q0 + fq * 16 + lg * 4 + r;
      u16* od = Ob + ((long)(b * TT + t)) * CDIM + h * HD;
#pragma unroll
      for (int fd = 0; fd < 8; ++fd) od[fd * 16 + lr] = f2bf(oacc[fq][fd][r] * inv);
    }
}

extern "C" void kernel_launch(void* const* d_in, const int* in_sizes, int n_in, void* d_out,
                              int out_size, void* d_ws, size_t ws_size, hipStream_t stream) {
  const float* x = (const float*)d_in[0];
  const float* wq = (const float*)d_in[2];
  const float* wk = (const float*)d_in[3];
  const float* wv = (const float*)d_in[4];
  const float* wo = (const float*)d_in[5];

  char* ws = (char*)d_ws;
  u16* xbf = (u16*)(ws);                   // 32 MB; later reused as attn-out [b][t][c]
  u16* wqkv = (u16*)(ws + 33554432);       // 24 MB  [6144][2048]
  u16* wobf = (u16*)(ws + 58720256);       // 8 MB
  u16* qbf = (u16*)(ws + 67108864);        // 32 MB  [b][h][t][d]
  u16* kbf = (u16*)(ws + 100663296);       // 32 MB
  u16* vbf = (u16*)(ws + 134217728);       // 32 MB
  float* cosT = (float*)(ws + 167772160);  // 64 KB
  float* sinT = (float*)(ws + 167837696);  // 64 KB

  cvt_bf16_kernel<<<8192, 256, 0, stream>>>(x, xbf, 2097152);
  cvt_w_kernel<<<8192, 256, 0, stream>>>(wq, wk, wv, wo, wqkv, wobf);
  rope_tables_kernel<<<64, 256, 0, stream>>>(cosT, sinT);

  gemm256<1><<<768, 512, 0, stream>>>(xbf, wqkv, nullptr, qbf, kbf, vbf, cosT, sinT, 8192, 6144,
                                      2048, 24);
  attn_kernel<<<1024, 256, 0, stream>>>(qbf, kbf, vbf, xbf);
  gemm256<0><<<256, 512, 0, stream>>>(xbf, wobf, (float*)d_out, nullptr, nullptr, nullptr, nullptr,
                                      nullptr, 8192, 2048, 2048, 8);
}

// Round 17
// 329.169 us; speedup vs baseline: 1.1588x; 1.0010x over previous
//
#include <hip/hip_runtime.h>

typedef unsigned short u16;
typedef unsigned int u32;
typedef __attribute__((ext_vector_type(4))) float f32x4;
typedef __attribute__((ext_vector_type(8))) short bf16x8;
typedef __attribute__((ext_vector_type(4))) unsigned short u16x4;
typedef __attribute__((ext_vector_type(8))) unsigned short u16x8;

#define NH 16
#define HD 128
#define TT 256
#define CDIM 2048

__device__ __forceinline__ u16 f2bf(float f) {
  u32 u = __float_as_uint(f);
  u = (u + 0x7fffu + ((u >> 16) & 1u)) >> 16;
  return (u16)u;
}
__device__ __forceinline__ float bf2f(u16 h) {
  return __uint_as_float(((u32)h) << 16);
}
__device__ __forceinline__ void gload_lds16(const u16* g, u16* l) {
  __builtin_amdgcn_global_load_lds((__attribute__((address_space(1))) void*)g,
                                   (__attribute__((address_space(3))) void*)l, 16, 0, 0);
}

#define BAR() __builtin_amdgcn_s_barrier()
#define SCB() __builtin_amdgcn_sched_barrier(0)
#define WV6()                                         \
  {                                                   \
    asm volatile("s_waitcnt vmcnt(6)" ::: "memory");  \
    SCB();                                            \
  }
#define WV8()                                         \
  {                                                   \
    asm volatile("s_waitcnt vmcnt(8)" ::: "memory");  \
    SCB();                                            \
  }
#define WVL0()                                                   \
  {                                                              \
    asm volatile("s_waitcnt vmcnt(0) lgkmcnt(0)" ::: "memory");  \
    SCB();                                                       \
  }
#define P1() __builtin_amdgcn_s_setprio(1)
#define P0() __builtin_amdgcn_s_setprio(0)

// ---------------- convert f32 -> bf16, 8 elems/thread ----------------
__global__ __launch_bounds__(256) void cvt_bf16_kernel(const float* __restrict__ src,
                                                       u16* __restrict__ dst, int n8) {
  int i = blockIdx.x * 256 + threadIdx.x;
  if (i >= n8) return;
  const float4* s4 = (const float4*)src;
  float4 a = s4[i * 2];
  float4 b = s4[i * 2 + 1];
  u16x8 r;
  r[0] = f2bf(a.x); r[1] = f2bf(a.y); r[2] = f2bf(a.z); r[3] = f2bf(a.w);
  r[4] = f2bf(b.x); r[5] = f2bf(b.y); r[6] = f2bf(b.z); r[7] = f2bf(b.w);
  *(u16x8*)(dst + (long)i * 8) = r;
}

// all four weight matrices in one launch
__global__ __launch_bounds__(256) void cvt_w_kernel(const float* __restrict__ wq,
                                                    const float* __restrict__ wk,
                                                    const float* __restrict__ wv,
                                                    const float* __restrict__ wo,
                                                    u16* __restrict__ wqkv,
                                                    u16* __restrict__ wobf) {
  int i = blockIdx.x * 256 + threadIdx.x;
  int seg = i >> 19;
  int r8 = i & 524287;
  const float* s = (seg == 0) ? wq : (seg == 1) ? wk : (seg == 2) ? wv : wo;
  u16* d = (seg == 3) ? wobf : (wqkv + (long)seg * 4194304);
  const float4* s4 = (const float4*)s;
  float4 a = s4[r8 * 2];
  float4 b = s4[r8 * 2 + 1];
  u16x8 r;
  r[0] = f2bf(a.x); r[1] = f2bf(a.y); r[2] = f2bf(a.z); r[3] = f2bf(a.w);
  r[4] = f2bf(b.x); r[5] = f2bf(b.y); r[6] = f2bf(b.z); r[7] = f2bf(b.w);
  *(u16x8*)(d + (long)r8 * 8) = r;
}

// ---------------- rope tables: [256][64] cos,sin ----------------
__global__ void rope_tables_kernel(float* __restrict__ cosT, float* __restrict__ sinT) {
  int i = blockIdx.x * 256 + threadIdx.x;  // 16384
  int t = i >> 6, d = i & 63;
  float inv = __expf(-(float)d * (9.210340371976184f / 64.0f));
  float a = (float)t * inv;
  cosT[i] = cosf(a);
  sinT[i] = sinf(a);
}

// ---------------- 256x256 GEMM  C = A * B^T ----------------
// R17: 2-phase loop, re-derived rotation with ZERO same-phase read/write
// region overlap (R16 had a latent CB.Bu2 race):
//   phase A reads {A,Bu0,Bu1}, stages OB.{Bu2,Bu3} <- t+1
//   phase B reads {Bu2,Bu3},  stages CB.{A0-3,Bu0,Bu1} <- t+2
// Both phases end WV8 (FIFO-traced: A/Bu0/Bu1 staged 2 iters prior, Bu2/Bu3
// 3 phases prior; 8 younger ops at each wait). NO forced lgkm drain before
// MFMA -- plain C++ ds_reads let the compiler emit fine-grained lgkmcnt and
// interleave reads under MFMA; the WV8 "memory" fences pin cross-phase order.
#define LDA_(CB)                                                     \
  _Pragma("unroll") for (int f = 0; f < 4; ++f)                      \
  _Pragma("unroll") for (int ks = 0; ks < 2; ++ks)                   \
      fa[f][ks] = *(const bf16x8*)&lds[(CB) + wr64 + f * 1024 + lb[ks]];

#define LDB_(FB, CB, Q)                                              \
  _Pragma("unroll") for (int fn = 0; fn < 2; ++fn)                   \
  _Pragma("unroll") for (int ks = 0; ks < 2; ++ks)                   \
      FB[fn][ks] = *(const bf16x8*)&lds[(CB) + wbB + (Q)*2048 + fn * 1024 + lb[ks]];

#define MMQ(FB, Q)                                                   \
  _Pragma("unroll") for (int ks = 0; ks < 2; ++ks)                   \
  _Pragma("unroll") for (int f = 0; f < 4; ++f)                      \
  _Pragma("unroll") for (int fn = 0; fn < 2; ++fn)                   \
      acc[f][(Q)*2 + fn] = __builtin_amdgcn_mfma_f32_16x16x32_bf16(  \
          fa[f][ks], FB[fn][ks], acc[f][(Q)*2 + fn], 0, 0, 0);

template <int MODE>
__global__ __launch_bounds__(512, 2) void gemm256(const u16* __restrict__ A,
                                                  const u16* __restrict__ Bt,
                                                  float* __restrict__ Cf, u16* __restrict__ Qo,
                                                  u16* __restrict__ Ko, u16* __restrict__ Vo,
                                                  const float* __restrict__ cosT,
                                                  const float* __restrict__ sinT,
                                                  int M, int N, int K, int GX) {
  __shared__ u16 lds[65536];  // buf c at c*32768: [A 4x4096][Bu0..Bu3 4x4096] u16
  const int wg = blockIdx.x;
  const int bn = wg % GX, bm = wg / GX;
  const int tid = threadIdx.x, wid = tid >> 6, lane = tid & 63;
  const int lr = lane & 15, lg = lane >> 4;
  const int wr = (wid >> 1) * 64;      // wave A-row base in [0,256)
  const int wch = wid & 1;             // wave B-half (C cols wch*128 .. +127)
  const int wr64 = (wid >> 1) * 4096;  // hoisted A base
  const int wbB = 16384 + wch * 8192;  // hoisted B base
  const int NT = K >> 6;
  const long KU = (long)64 * K;
  const u16* Ag = A + (long)(bm * 256) * K;
  const u16* Bg = Bt + (long)(bn * 256) * K;

  int lb[2];
#pragma unroll
  for (int ks = 0; ks < 2; ++ks) lb[ks] = lr * 64 + (((ks * 4 + lg) ^ (lr & 7))) * 8;

  const int csg = ((tid & 7) ^ ((tid >> 3) & 7)) * 8;
  const u16* aBase = Ag + (long)(tid >> 3) * K + csg;
  const u16* bBase = Bg + (long)(tid >> 3) * K + csg;
  auto STGA = [&](int ldso, int u, int kt) {
    if (kt > NT - 1) kt = NT - 1;
    gload_lds16(aBase + (long)u * KU + kt * 64, &lds[ldso + tid * 8]);
  };
  auto STGB = [&](int ldso, int u, int kt) {
    if (kt > NT - 1) kt = NT - 1;
    gload_lds16(bBase + (long)u * KU + kt * 64, &lds[ldso + tid * 8]);
  };

  bf16x8 fa[4][2], fbA[2][2], fbB[2][2];
  const f32x4 zero = {0.f, 0.f, 0.f, 0.f};
  f32x4 acc[4][8];
#pragma unroll
  for (int a = 0; a < 4; ++a)
#pragma unroll
    for (int b = 0; b < 8; ++b) acc[a][b] = zero;

  // prologue: buf0 full (8), buf1 {A0-3,Bu0,Bu1} (6); WV6 drains buf0 only
  STGA(0, 0, 0);
  STGA(4096, 1, 0);
  STGA(8192, 2, 0);
  STGA(12288, 3, 0);
  STGB(16384, 0, 0);
  STGB(20480, 1, 0);
  STGB(24576, 2, 0);
  STGB(28672, 3, 0);
  STGA(32768, 0, 1);
  STGA(36864, 1, 1);
  STGA(40960, 2, 1);
  STGA(45056, 3, 1);
  STGB(49152, 0, 1);
  STGB(53248, 1, 1);
  WV6();
  BAR();

#define TILE2(CB, OB, T1, T2)          \
  LDA_(CB)                             \
  LDB_(fbA, CB, 0)                     \
  LDB_(fbB, CB, 1)                     \
  STGB((OB) + 24576, 2, T1);           \
  STGB((OB) + 28672, 3, T1);           \
  P1(); MMQ(fbA, 0) MMQ(fbB, 1) P0(); \
  WV8();                               \
  BAR();                               \
  LDB_(fbA, CB, 2)                     \
  LDB_(fbB, CB, 3)                     \
  STGA((CB) + 0, 0, T2);               \
  STGA((CB) + 4096, 1, T2);            \
  STGA((CB) + 8192, 2, T2);            \
  STGA((CB) + 12288, 3, T2);           \
  STGB((CB) + 16384, 0, T2);           \
  STGB((CB) + 20480, 1, T2);           \
  P1(); MMQ(fbA, 2) MMQ(fbB, 3) P0(); \
  WV8();                               \
  BAR();

  const int J = NT >> 1;
  for (int j = 0; j < J; ++j) {
    const int t1 = 2 * j + 1, t2 = 2 * j + 2, t3 = 2 * j + 3;
    TILE2(0, 32768, t1, t2)
    TILE2(32768, 0, t2, t3)
  }
  WVL0();
  BAR();

  if (MODE == 0) {
#pragma unroll
    for (int f = 0; f < 4; ++f)
#pragma unroll
      for (int j8 = 0; j8 < 8; ++j8)
#pragma unroll
        for (int r = 0; r < 4; ++r) {
          int m = bm * 256 + wr + f * 16 + lg * 4 + r;
          int n = bn * 256 + wch * 128 + (j8 >> 1) * 32 + (j8 & 1) * 16 + lr;
          Cf[(long)m * N + n] = acc[f][j8][r];
        }
  } else {
    const int mat = bn >> 3;
    u16* dst = (mat == 0) ? Qo : ((mat == 1) ? Ko : Vo);
    const float qsc = (mat == 0) ? 0.08838834764831845f : 1.0f;
#pragma unroll
    for (int mh = 0; mh < 2; ++mh) {
      if (mh) BAR();
      if ((wid >> 2) == mh) {
#pragma unroll
        for (int f = 0; f < 4; ++f)
#pragma unroll
          for (int j8 = 0; j8 < 8; ++j8)
#pragma unroll
            for (int r = 0; r < 4; ++r) {
              int rowl = ((wid >> 1) & 1) * 64 + f * 16 + lg * 4 + r;
              int col = wch * 128 + (j8 >> 1) * 32 + (j8 & 1) * 16 + lr;
              lds[rowl * 272 + col] = f2bf(acc[f][j8][r]);
            }
      }
      BAR();
#pragma unroll
      for (int it = 0; it < 8; ++it) {
        int task = it * 512 + tid;
        int tl = task >> 5, c8 = task & 31;
        int hp = c8 >> 4, d0 = (c8 & 15) * 8;
        int t = mh * 128 + tl;
        int head = (bn * 2 + hp) & 15;
        u16x8 v1 = *(const u16x8*)&lds[tl * 272 + hp * 128 + d0];
        u16x8 o;
        if (mat < 2) {
          int dpart = (d0 < 64) ? (d0 + 64) : (d0 - 64);
          u16x8 v2 = *(const u16x8*)&lds[tl * 272 + hp * 128 + dpart];
          int dm = d0 & 63;
          float4 c0 = *(const float4*)(cosT + t * 64 + dm);
          float4 c1 = *(const float4*)(cosT + t * 64 + dm + 4);
          float4 s0 = *(const float4*)(sinT + t * 64 + dm);
          float4 s1 = *(const float4*)(sinT + t * 64 + dm + 4);
          float cc[8] = {c0.x, c0.y, c0.z, c0.w, c1.x, c1.y, c1.z, c1.w};
          float ss[8] = {s0.x, s0.y, s0.z, s0.w, s1.x, s1.y, s1.z, s1.w};
          float sgn = (d0 < 64) ? -1.f : 1.f;
#pragma unroll
          for (int jj = 0; jj < 8; ++jj)
            o[jj] = f2bf((bf2f(v1[jj]) * cc[jj] + sgn * bf2f(v2[jj]) * ss[jj]) * qsc);
        } else {
          o = v1;
        }
        *(u16x8*)(dst + (((long)(bm * NH + head)) * TT + t) * HD + d0) = o;
      }
    }
  }
}

// ---------------- fused causal attention (R15, frozen) ----------------
__global__ __launch_bounds__(256, 2) void attn_kernel(const u16* __restrict__ Qb,
                                                      const u16* __restrict__ Kb,
                                                      const u16* __restrict__ Vb,
                                                      u16* __restrict__ Ob) {
  __shared__ u16 Ks[64][136];
  __shared__ u16 Vt[128][72];
  __shared__ u16 Ps[4][32][72];
  const int bid = blockIdx.x;
  const int qb = (bid < 512) ? 1 : 0;
  const int hb = (bid < 512) ? bid : (bid - 512);
  const int h = hb & 15, b = hb >> 4;
  const int tid = threadIdx.x, wid = tid >> 6, lane = tid & 63;
  const int lr = lane & 15, lg = lane >> 4;
  const u16* qh = Qb + ((long)(b * NH + h)) * TT * HD;
  const u16* kh = Kb + ((long)(b * NH + h)) * TT * HD;
  const u16* vh = Vb + ((long)(b * NH + h)) * TT * HD;
  const int q0 = qb * 128 + wid * 32;

  bf16x8 qf[2][4];
#pragma unroll
  for (int fq = 0; fq < 2; ++fq)
#pragma unroll
    for (int ds = 0; ds < 4; ++ds)
      qf[fq][ds] = *(const bf16x8*)(qh + (long)(q0 + fq * 16 + lr) * HD + ds * 32 + lg * 8);

  const f32x4 zero = {0.f, 0.f, 0.f, 0.f};
  f32x4 oacc[2][8];
#pragma unroll
  for (int fq = 0; fq < 2; ++fq)
#pragma unroll
    for (int fd = 0; fd < 8; ++fd) oacc[fq][fd] = zero;
  float mrow[2][4], lrow[2][4];
#pragma unroll
  for (int fq = 0; fq < 2; ++fq)
#pragma unroll
    for (int r = 0; r < 4; ++r) { mrow[fq][r] = -1e30f; lrow[fq][r] = 0.f; }

  const int nch = (qb == 0) ? 2 : 4;
  for (int kc = 0; kc < nch; ++kc) {
    __syncthreads();
#pragma unroll
    for (int it = 0; it < 4; ++it) {
      int task = it * 256 + tid;
      int r = task >> 4, sg = task & 15;
      u16x8 v = *(const u16x8*)(kh + (long)(kc * 64 + r) * HD + sg * 8);
      *(u16x8*)(&Ks[r][sg * 8]) = v;
    }
#pragma unroll
    for (int it = 0; it < 4; ++it) {
      int task = it * 256 + tid;
      int r = task >> 4, d0 = (task & 15) * 8;
      u16x8 v = *(const u16x8*)(vh + (long)(kc * 64 + r) * HD + d0);
#pragma unroll
      for (int j = 0; j < 8; ++j) Vt[d0 + j][r] = v[j];
    }
    __syncthreads();

    f32x4 sacc[2][4];
#pragma unroll
    for (int fq = 0; fq < 2; ++fq)
#pragma unroll
      for (int fk = 0; fk < 4; ++fk) sacc[fq][fk] = zero;
#pragma unroll
    for (int ds = 0; ds < 4; ++ds) {
      bf16x8 kf[4];
#pragma unroll
      for (int fk = 0; fk < 4; ++fk)
        kf[fk] = *(const bf16x8*)(&Ks[fk * 16 + lr][ds * 32 + lg * 8]);
#pragma unroll
      for (int fq = 0; fq < 2; ++fq)
#pragma unroll
        for (int fk = 0; fk < 4; ++fk)
          sacc[fq][fk] =
              __builtin_amdgcn_mfma_f32_16x16x32_bf16(qf[fq][ds], kf[fk], sacc[fq][fk], 0, 0, 0);
    }

#pragma unroll
    for (int fq = 0; fq < 2; ++fq) {
      float mnew[4], alpha[4], psum[4];
#pragma unroll
      for (int r = 0; r < 4; ++r) {
        int qrow = q0 + fq * 16 + lg * 4 + r;
        float cmax = -1e30f;
#pragma unroll
        for (int fk = 0; fk < 4; ++fk) {
          int kcol = kc * 64 + fk * 16 + lr;
          float s = sacc[fq][fk][r];
          if (kcol > qrow) s = -1e30f;
          sacc[fq][fk][r] = s;
          cmax = fmaxf(cmax, s);
        }
#pragma unroll
        for (int off = 1; off < 16; off <<= 1) cmax = fmaxf(cmax, __shfl_xor(cmax, off));
        mnew[r] = fmaxf(mrow[fq][r], cmax);
        alpha[r] = __expf(mrow[fq][r] - mnew[r]);
        mrow[fq][r] = mnew[r];
        psum[r] = 0.f;
      }
#pragma unroll
      for (int fk = 0; fk < 4; ++fk)
#pragma unroll
        for (int r = 0; r < 4; ++r) {
          float p = __expf(sacc[fq][fk][r] - mnew[r]);
          psum[r] += p;
          Ps[wid][fq * 16 + lg * 4 + r][fk * 16 + lr] = f2bf(p);
        }
#pragma unroll
      for (int r = 0; r < 4; ++r) {
        float ps = psum[r];
#pragma unroll
        for (int off = 1; off < 16; off <<= 1) ps += __shfl_xor(ps, off);
        lrow[fq][r] = lrow[fq][r] * alpha[r] + ps;
#pragma unroll
        for (int fd = 0; fd < 8; ++fd) oacc[fq][fd][r] *= alpha[r];
      }
    }

#pragma unroll
    for (int ks = 0; ks < 2; ++ks) {
      bf16x8 pf0 = *(const bf16x8*)(&Ps[wid][lr][ks * 32 + lg * 8]);
      bf16x8 pf1 = *(const bf16x8*)(&Ps[wid][16 + lr][ks * 32 + lg * 8]);
#pragma unroll
      for (int fd = 0; fd < 8; ++fd) {
        bf16x8 vf = *(const bf16x8*)(&Vt[fd * 16 + lr][ks * 32 + lg * 8]);
        oacc[0][fd] = __builtin_amdgcn_mfma_f32_16x16x32_bf16(pf0, vf, oacc[0][fd], 0, 0, 0);
        oacc[1][fd] = __builtin_amdgcn_mfma_f32_16x16x32_bf16(pf1, vf, oacc[1][fd], 0, 0, 0);
      }
    }
  }

#pragma unroll
  for (int fq = 0; fq < 2; ++fq)
#pragma unroll
    for (int r = 0; r < 4; ++r) {
      float inv = 1.0f / lrow[fq][r];
      int t = q0 + fq * 16 + lg * 4 + r;
      u16* od = Ob + ((long)(b * TT + t)) * CDIM + h * HD;
#pragma unroll
      for (int fd = 0; fd < 8; ++fd) od[fd * 16 + lr] = f2bf(oacc[fq][fd][r] * inv);
    }
}

extern "C" void kernel_launch(void* const* d_in, const int* in_sizes, int n_in, void* d_out,
                              int out_size, void* d_ws, size_t ws_size, hipStream_t stream) {
  const float* x = (const float*)d_in[0];
  const float* wq = (const float*)d_in[2];
  const float* wk = (const float*)d_in[3];
  const float* wv = (const float*)d_in[4];
  const float* wo = (const float*)d_in[5];

  char* ws = (char*)d_ws;
  u16* xbf = (u16*)(ws);                   // 32 MB; later reused as attn-out [b][t][c]
  u16* wqkv = (u16*)(ws + 33554432);       // 24 MB  [6144][2048]
  u16* wobf = (u16*)(ws + 58720256);       // 8 MB
  u16* qbf = (u16*)(ws + 67108864);        // 32 MB  [b][h][t][d]
  u16* kbf = (u16*)(ws + 100663296);       // 32 MB
  u16* vbf = (u16*)(ws + 134217728);       // 32 MB
  float* cosT = (float*)(ws + 167772160);  // 64 KB
  float* sinT = (float*)(ws + 167837696);  // 64 KB

  cvt_bf16_kernel<<<8192, 256, 0, stream>>>(x, xbf, 2097152);
  cvt_w_kernel<<<8192, 256, 0, stream>>>(wq, wk, wv, wo, wqkv, wobf);
  rope_tables_kernel<<<64, 256, 0, stream>>>(cosT, sinT);

  gemm256<1><<<768, 512, 0, stream>>>(xbf, wqkv, nullptr, qbf, kbf, vbf, cosT, sinT, 8192, 6144,
                                      2048, 24);
  attn_kernel<<<1024, 256, 0, stream>>>(qbf, kbf, vbf, xbf);
  gemm256<0><<<256, 512, 0, stream>>>(xbf, wobf, (float*)d_out, nullptr, nullptr, nullptr, nullptr,
                                      nullptr, 8192, 2048, 2048, 8);
}

// Round 18
// 324.618 us; speedup vs baseline: 1.1751x; 1.0140x over previous
//
#include <hip/hip_runtime.h>

typedef unsigned short u16;
typedef unsigned int u32;
typedef __attribute__((ext_vector_type(4))) float f32x4;
typedef __attribute__((ext_vector_type(8))) short bf16x8;
typedef __attribute__((ext_vector_type(4))) unsigned short u16x4;
typedef __attribute__((ext_vector_type(8))) unsigned short u16x8;

#define NH 16
#define HD 128
#define TT 256
#define CDIM 2048

__device__ __forceinline__ u16 f2bf(float f) {
  u32 u = __float_as_uint(f);
  u = (u + 0x7fffu + ((u >> 16) & 1u)) >> 16;
  return (u16)u;
}
__device__ __forceinline__ float bf2f(u16 h) {
  return __uint_as_float(((u32)h) << 16);
}
__device__ __forceinline__ void gload_lds16(const u16* g, u16* l) {
  __builtin_amdgcn_global_load_lds((__attribute__((address_space(1))) void*)g,
                                   (__attribute__((address_space(3))) void*)l, 16, 0, 0);
}

#define BAR() __builtin_amdgcn_s_barrier()
#define SCB() __builtin_amdgcn_sched_barrier(0)
#define WV6()                                         \
  {                                                   \
    asm volatile("s_waitcnt vmcnt(6)" ::: "memory");  \
    SCB();                                            \
  }
#define WV8()                                         \
  {                                                   \
    asm volatile("s_waitcnt vmcnt(8)" ::: "memory");  \
    SCB();                                            \
  }
#define WVL0()                                                   \
  {                                                              \
    asm volatile("s_waitcnt vmcnt(0) lgkmcnt(0)" ::: "memory");  \
    SCB();                                                       \
  }
#define P1() __builtin_amdgcn_s_setprio(1)
#define P0() __builtin_amdgcn_s_setprio(0)

// ---------------- fused prep: x->bf16, weights->bf16, rope tables ----------------
// blocks [0,8192): x (f32->bf16, 8 elems/thread)
// blocks [8192,16384): the 4 weight matrices
// blocks [16384,16448): cos/sin tables
__global__ __launch_bounds__(256) void prep_kernel(const float* __restrict__ x,
                                                   const float* __restrict__ wq,
                                                   const float* __restrict__ wk,
                                                   const float* __restrict__ wv,
                                                   const float* __restrict__ wo,
                                                   u16* __restrict__ xbf,
                                                   u16* __restrict__ wqkv,
                                                   u16* __restrict__ wobf,
                                                   float* __restrict__ cosT,
                                                   float* __restrict__ sinT) {
  int blk = blockIdx.x;
  if (blk < 8192) {
    int i = blk * 256 + threadIdx.x;
    const float4* s4 = (const float4*)x;
    float4 a = s4[i * 2];
    float4 b = s4[i * 2 + 1];
    u16x8 r;
    r[0] = f2bf(a.x); r[1] = f2bf(a.y); r[2] = f2bf(a.z); r[3] = f2bf(a.w);
    r[4] = f2bf(b.x); r[5] = f2bf(b.y); r[6] = f2bf(b.z); r[7] = f2bf(b.w);
    *(u16x8*)(xbf + (long)i * 8) = r;
  } else if (blk < 16384) {
    int i = (blk - 8192) * 256 + threadIdx.x;
    int seg = i >> 19;
    int r8 = i & 524287;
    const float* s = (seg == 0) ? wq : (seg == 1) ? wk : (seg == 2) ? wv : wo;
    u16* d = (seg == 3) ? wobf : (wqkv + (long)seg * 4194304);
    const float4* s4 = (const float4*)s;
    float4 a = s4[r8 * 2];
    float4 b = s4[r8 * 2 + 1];
    u16x8 r;
    r[0] = f2bf(a.x); r[1] = f2bf(a.y); r[2] = f2bf(a.z); r[3] = f2bf(a.w);
    r[4] = f2bf(b.x); r[5] = f2bf(b.y); r[6] = f2bf(b.z); r[7] = f2bf(b.w);
    *(u16x8*)(d + (long)r8 * 8) = r;
  } else {
    int i = (blk - 16384) * 256 + threadIdx.x;  // 16384 tasks
    int t = i >> 6, d = i & 63;
    float inv = __expf(-(float)d * (9.210340371976184f / 64.0f));
    float a = (float)t * inv;
    cosT[i] = cosf(a);
    sinT[i] = sinf(a);
  }
}

// ---------------- 256x256 GEMM  C = A * B^T (R17 structure, frozen) ----------------
// 2-phase loop, zero same-phase read/write region overlap:
//   phase A reads {A,Bu0,Bu1}, stages OB.{Bu2,Bu3} <- t+1
//   phase B reads {Bu2,Bu3},  stages CB.{A0-3,Bu0,Bu1} <- t+2
// Both phases end WV8 (FIFO-traced). No forced lgkm drain before MFMA.
#define LDA_(CB)                                                     \
  _Pragma("unroll") for (int f = 0; f < 4; ++f)                      \
  _Pragma("unroll") for (int ks = 0; ks < 2; ++ks)                   \
      fa[f][ks] = *(const bf16x8*)&lds[(CB) + wr64 + f * 1024 + lb[ks]];

#define LDB_(FB, CB, Q)                                              \
  _Pragma("unroll") for (int fn = 0; fn < 2; ++fn)                   \
  _Pragma("unroll") for (int ks = 0; ks < 2; ++ks)                   \
      FB[fn][ks] = *(const bf16x8*)&lds[(CB) + wbB + (Q)*2048 + fn * 1024 + lb[ks]];

#define MMQ(FB, Q)                                                   \
  _Pragma("unroll") for (int ks = 0; ks < 2; ++ks)                   \
  _Pragma("unroll") for (int f = 0; f < 4; ++f)                      \
  _Pragma("unroll") for (int fn = 0; fn < 2; ++fn)                   \
      acc[f][(Q)*2 + fn] = __builtin_amdgcn_mfma_f32_16x16x32_bf16(  \
          fa[f][ks], FB[fn][ks], acc[f][(Q)*2 + fn], 0, 0, 0);

template <int MODE>
__global__ __launch_bounds__(512, 2) void gemm256(const u16* __restrict__ A,
                                                  const u16* __restrict__ Bt,
                                                  float* __restrict__ Cf, u16* __restrict__ Qo,
                                                  u16* __restrict__ Ko, u16* __restrict__ Vo,
                                                  const float* __restrict__ cosT,
                                                  const float* __restrict__ sinT,
                                                  int M, int N, int K, int GX) {
  __shared__ u16 lds[65536];  // buf c at c*32768: [A 4x4096][Bu0..Bu3 4x4096] u16
  const int wg = blockIdx.x;
  const int bn = wg % GX, bm = wg / GX;
  const int tid = threadIdx.x, wid = tid >> 6, lane = tid & 63;
  const int lr = lane & 15, lg = lane >> 4;
  const int wr = (wid >> 1) * 64;
  const int wch = wid & 1;
  const int wr64 = (wid >> 1) * 4096;
  const int wbB = 16384 + wch * 8192;
  const int NT = K >> 6;
  const long KU = (long)64 * K;
  const u16* Ag = A + (long)(bm * 256) * K;
  const u16* Bg = Bt + (long)(bn * 256) * K;

  int lb[2];
#pragma unroll
  for (int ks = 0; ks < 2; ++ks) lb[ks] = lr * 64 + (((ks * 4 + lg) ^ (lr & 7))) * 8;

  const int csg = ((tid & 7) ^ ((tid >> 3) & 7)) * 8;
  const u16* aBase = Ag + (long)(tid >> 3) * K + csg;
  const u16* bBase = Bg + (long)(tid >> 3) * K + csg;
  auto STGA = [&](int ldso, int u, int kt) {
    if (kt > NT - 1) kt = NT - 1;
    gload_lds16(aBase + (long)u * KU + kt * 64, &lds[ldso + tid * 8]);
  };
  auto STGB = [&](int ldso, int u, int kt) {
    if (kt > NT - 1) kt = NT - 1;
    gload_lds16(bBase + (long)u * KU + kt * 64, &lds[ldso + tid * 8]);
  };

  bf16x8 fa[4][2], fbA[2][2], fbB[2][2];
  const f32x4 zero = {0.f, 0.f, 0.f, 0.f};
  f32x4 acc[4][8];
#pragma unroll
  for (int a = 0; a < 4; ++a)
#pragma unroll
    for (int b = 0; b < 8; ++b) acc[a][b] = zero;

  STGA(0, 0, 0);
  STGA(4096, 1, 0);
  STGA(8192, 2, 0);
  STGA(12288, 3, 0);
  STGB(16384, 0, 0);
  STGB(20480, 1, 0);
  STGB(24576, 2, 0);
  STGB(28672, 3, 0);
  STGA(32768, 0, 1);
  STGA(36864, 1, 1);
  STGA(40960, 2, 1);
  STGA(45056, 3, 1);
  STGB(49152, 0, 1);
  STGB(53248, 1, 1);
  WV6();
  BAR();

#define TILE2(CB, OB, T1, T2)          \
  LDA_(CB)                             \
  LDB_(fbA, CB, 0)                     \
  LDB_(fbB, CB, 1)                     \
  STGB((OB) + 24576, 2, T1);           \
  STGB((OB) + 28672, 3, T1);           \
  P1(); MMQ(fbA, 0) MMQ(fbB, 1) P0(); \
  WV8();                               \
  BAR();                               \
  LDB_(fbA, CB, 2)                     \
  LDB_(fbB, CB, 3)                     \
  STGA((CB) + 0, 0, T2);               \
  STGA((CB) + 4096, 1, T2);            \
  STGA((CB) + 8192, 2, T2);            \
  STGA((CB) + 12288, 3, T2);           \
  STGB((CB) + 16384, 0, T2);           \
  STGB((CB) + 20480, 1, T2);           \
  P1(); MMQ(fbA, 2) MMQ(fbB, 3) P0(); \
  WV8();                               \
  BAR();

  const int J = NT >> 1;
  for (int j = 0; j < J; ++j) {
    const int t1 = 2 * j + 1, t2 = 2 * j + 2, t3 = 2 * j + 3;
    TILE2(0, 32768, t1, t2)
    TILE2(32768, 0, t2, t3)
  }
  WVL0();
  BAR();

  if (MODE == 0) {
#pragma unroll
    for (int f = 0; f < 4; ++f)
#pragma unroll
      for (int j8 = 0; j8 < 8; ++j8)
#pragma unroll
        for (int r = 0; r < 4; ++r) {
          int m = bm * 256 + wr + f * 16 + lg * 4 + r;
          int n = bn * 256 + wch * 128 + (j8 >> 1) * 32 + (j8 & 1) * 16 + lr;
          Cf[(long)m * N + n] = acc[f][j8][r];
        }
  } else {
    const int mat = bn >> 3;
    u16* dst = (mat == 0) ? Qo : ((mat == 1) ? Ko : Vo);
    const float qsc = (mat == 0) ? 0.08838834764831845f : 1.0f;
#pragma unroll
    for (int mh = 0; mh < 2; ++mh) {
      if (mh) BAR();
      if ((wid >> 2) == mh) {
#pragma unroll
        for (int f = 0; f < 4; ++f)
#pragma unroll
          for (int j8 = 0; j8 < 8; ++j8)
#pragma unroll
            for (int r = 0; r < 4; ++r) {
              int rowl = ((wid >> 1) & 1) * 64 + f * 16 + lg * 4 + r;
              int col = wch * 128 + (j8 >> 1) * 32 + (j8 & 1) * 16 + lr;
              lds[rowl * 272 + col] = f2bf(acc[f][j8][r]);
            }
      }
      BAR();
#pragma unroll
      for (int it = 0; it < 8; ++it) {
        int task = it * 512 + tid;
        int tl = task >> 5, c8 = task & 31;
        int hp = c8 >> 4, d0 = (c8 & 15) * 8;
        int t = mh * 128 + tl;
        int head = (bn * 2 + hp) & 15;
        u16x8 v1 = *(const u16x8*)&lds[tl * 272 + hp * 128 + d0];
        u16x8 o;
        if (mat < 2) {
          int dpart = (d0 < 64) ? (d0 + 64) : (d0 - 64);
          u16x8 v2 = *(const u16x8*)&lds[tl * 272 + hp * 128 + dpart];
          int dm = d0 & 63;
          float4 c0 = *(const float4*)(cosT + t * 64 + dm);
          float4 c1 = *(const float4*)(cosT + t * 64 + dm + 4);
          float4 s0 = *(const float4*)(sinT + t * 64 + dm);
          float4 s1 = *(const float4*)(sinT + t * 64 + dm + 4);
          float cc[8] = {c0.x, c0.y, c0.z, c0.w, c1.x, c1.y, c1.z, c1.w};
          float ss[8] = {s0.x, s0.y, s0.z, s0.w, s1.x, s1.y, s1.z, s1.w};
          float sgn = (d0 < 64) ? -1.f : 1.f;
#pragma unroll
          for (int jj = 0; jj < 8; ++jj)
            o[jj] = f2bf((bf2f(v1[jj]) * cc[jj] + sgn * bf2f(v2[jj]) * ss[jj]) * qsc);
        } else {
          o = v1;
        }
        *(u16x8*)(dst + (((long)(bm * NH + head)) * TT + t) * HD + d0) = o;
      }
    }
  }
}

// ---------------- fused causal attention (R15, frozen) ----------------
__global__ __launch_bounds__(256, 2) void attn_kernel(const u16* __restrict__ Qb,
                                                      const u16* __restrict__ Kb,
                                                      const u16* __restrict__ Vb,
                                                      u16* __restrict__ Ob) {
  __shared__ u16 Ks[64][136];
  __shared__ u16 Vt[128][72];
  __shared__ u16 Ps[4][32][72];
  const int bid = blockIdx.x;
  const int qb = (bid < 512) ? 1 : 0;
  const int hb = (bid < 512) ? bid : (bid - 512);
  const int h = hb & 15, b = hb >> 4;
  const int tid = threadIdx.x, wid = tid >> 6, lane = tid & 63;
  const int lr = lane & 15, lg = lane >> 4;
  const u16* qh = Qb + ((long)(b * NH + h)) * TT * HD;
  const u16* kh = Kb + ((long)(b * NH + h)) * TT * HD;
  const u16* vh = Vb + ((long)(b * NH + h)) * TT * HD;
  const int q0 = qb * 128 + wid * 32;

  bf16x8 qf[2][4];
#pragma unroll
  for (int fq = 0; fq < 2; ++fq)
#pragma unroll
    for (int ds = 0; ds < 4; ++ds)
      qf[fq][ds] = *(const bf16x8*)(qh + (long)(q0 + fq * 16 + lr) * HD + ds * 32 + lg * 8);

  const f32x4 zero = {0.f, 0.f, 0.f, 0.f};
  f32x4 oacc[2][8];
#pragma unroll
  for (int fq = 0; fq < 2; ++fq)
#pragma unroll
    for (int fd = 0; fd < 8; ++fd) oacc[fq][fd] = zero;
  float mrow[2][4], lrow[2][4];
#pragma unroll
  for (int fq = 0; fq < 2; ++fq)
#pragma unroll
    for (int r = 0; r < 4; ++r) { mrow[fq][r] = -1e30f; lrow[fq][r] = 0.f; }

  const int nch = (qb == 0) ? 2 : 4;
  for (int kc = 0; kc < nch; ++kc) {
    __syncthreads();
#pragma unroll
    for (int it = 0; it < 4; ++it) {
      int task = it * 256 + tid;
      int r = task >> 4, sg = task & 15;
      u16x8 v = *(const u16x8*)(kh + (long)(kc * 64 + r) * HD + sg * 8);
      *(u16x8*)(&Ks[r][sg * 8]) = v;
    }
#pragma unroll
    for (int it = 0; it < 4; ++it) {
      int task = it * 256 + tid;
      int r = task >> 4, d0 = (task & 15) * 8;
      u16x8 v = *(const u16x8*)(vh + (long)(kc * 64 + r) * HD + d0);
#pragma unroll
      for (int j = 0; j < 8; ++j) Vt[d0 + j][r] = v[j];
    }
    __syncthreads();

    f32x4 sacc[2][4];
#pragma unroll
    for (int fq = 0; fq < 2; ++fq)
#pragma unroll
      for (int fk = 0; fk < 4; ++fk) sacc[fq][fk] = zero;
#pragma unroll
    for (int ds = 0; ds < 4; ++ds) {
      bf16x8 kf[4];
#pragma unroll
      for (int fk = 0; fk < 4; ++fk)
        kf[fk] = *(const bf16x8*)(&Ks[fk * 16 + lr][ds * 32 + lg * 8]);
#pragma unroll
      for (int fq = 0; fq < 2; ++fq)
#pragma unroll
        for (int fk = 0; fk < 4; ++fk)
          sacc[fq][fk] =
              __builtin_amdgcn_mfma_f32_16x16x32_bf16(qf[fq][ds], kf[fk], sacc[fq][fk], 0, 0, 0);
    }

#pragma unroll
    for (int fq = 0; fq < 2; ++fq) {
      float mnew[4], alpha[4], psum[4];
#pragma unroll
      for (int r = 0; r < 4; ++r) {
        int qrow = q0 + fq * 16 + lg * 4 + r;
        float cmax = -1e30f;
#pragma unroll
        for (int fk = 0; fk < 4; ++fk) {
          int kcol = kc * 64 + fk * 16 + lr;
          float s = sacc[fq][fk][r];
          if (kcol > qrow) s = -1e30f;
          sacc[fq][fk][r] = s;
          cmax = fmaxf(cmax, s);
        }
#pragma unroll
        for (int off = 1; off < 16; off <<= 1) cmax = fmaxf(cmax, __shfl_xor(cmax, off));
        mnew[r] = fmaxf(mrow[fq][r], cmax);
        alpha[r] = __expf(mrow[fq][r] - mnew[r]);
        mrow[fq][r] = mnew[r];
        psum[r] = 0.f;
      }
#pragma unroll
      for (int fk = 0; fk < 4; ++fk)
#pragma unroll
        for (int r = 0; r < 4; ++r) {
          float p = __expf(sacc[fq][fk][r] - mnew[r]);
          psum[r] += p;
          Ps[wid][fq * 16 + lg * 4 + r][fk * 16 + lr] = f2bf(p);
        }
#pragma unroll
      for (int r = 0; r < 4; ++r) {
        float ps = psum[r];
#pragma unroll
        for (int off = 1; off < 16; off <<= 1) ps += __shfl_xor(ps, off);
        lrow[fq][r] = lrow[fq][r] * alpha[r] + ps;
#pragma unroll
        for (int fd = 0; fd < 8; ++fd) oacc[fq][fd][r] *= alpha[r];
      }
    }

#pragma unroll
    for (int ks = 0; ks < 2; ++ks) {
      bf16x8 pf0 = *(const bf16x8*)(&Ps[wid][lr][ks * 32 + lg * 8]);
      bf16x8 pf1 = *(const bf16x8*)(&Ps[wid][16 + lr][ks * 32 + lg * 8]);
#pragma unroll
      for (int fd = 0; fd < 8; ++fd) {
        bf16x8 vf = *(const bf16x8*)(&Vt[fd * 16 + lr][ks * 32 + lg * 8]);
        oacc[0][fd] = __builtin_amdgcn_mfma_f32_16x16x32_bf16(pf0, vf, oacc[0][fd], 0, 0, 0);
        oacc[1][fd] = __builtin_amdgcn_mfma_f32_16x16x32_bf16(pf1, vf, oacc[1][fd], 0, 0, 0);
      }
    }
  }

#pragma unroll
  for (int fq = 0; fq < 2; ++fq)
#pragma unroll
    for (int r = 0; r < 4; ++r) {
      float inv = 1.0f / lrow[fq][r];
      int t = q0 + fq * 16 + lg * 4 + r;
      u16* od = Ob + ((long)(b * TT + t)) * CDIM + h * HD;
#pragma unroll
      for (int fd = 0; fd < 8; ++fd) od[fd * 16 + lr] = f2bf(oacc[fq][fd][r] * inv);
    }
}

extern "C" void kernel_launch(void* const* d_in, const int* in_sizes, int n_in, void* d_out,
                              int out_size, void* d_ws, size_t ws_size, hipStream_t stream) {
  const float* x = (const float*)d_in[0];
  const float* wq = (const float*)d_in[2];
  const float* wk = (const float*)d_in[3];
  const float* wv = (const float*)d_in[4];
  const float* wo = (const float*)d_in[5];

  char* ws = (char*)d_ws;
  u16* xbf = (u16*)(ws);                   // 32 MB; later reused as attn-out [b][t][c]
  u16* wqkv = (u16*)(ws + 33554432);       // 24 MB  [6144][2048]
  u16* wobf = (u16*)(ws + 58720256);       // 8 MB
  u16* qbf = (u16*)(ws + 67108864);        // 32 MB  [b][h][t][d]
  u16* kbf = (u16*)(ws + 100663296);       // 32 MB
  u16* vbf = (u16*)(ws + 134217728);       // 32 MB
  float* cosT = (float*)(ws + 167772160);  // 64 KB
  float* sinT = (float*)(ws + 167837696);  // 64 KB

  prep_kernel<<<16448, 256, 0, stream>>>(x, wq, wk, wv, wo, xbf, wqkv, wobf, cosT, sinT);

  gemm256<1><<<768, 512, 0, stream>>>(xbf, wqkv, nullptr, qbf, kbf, vbf, cosT, sinT, 8192, 6144,
                                      2048, 24);
  attn_kernel<<<1024, 256, 0, stream>>>(qbf, kbf, vbf, xbf);
  gemm256<0><<<256, 512, 0, stream>>>(xbf, wobf, (float*)d_out, nullptr, nullptr, nullptr, nullptr,
                                      nullptr, 8192, 2048, 2048, 8);
}